// Round 3
// baseline (786.385 us; speedup 1.0000x reference)
//
#include <hip/hip_runtime.h>
#include <cstdint>
#include <cstddef>

using u16 = unsigned short;
using u32 = unsigned int;

typedef __bf16 bf16x8 __attribute__((ext_vector_type(8)));
typedef float  f32x4  __attribute__((ext_vector_type(4)));

#define DI __device__ __forceinline__

constexpr int Hdim = 1536;
constexpr int NHq = 12, NKVh = 4, Dh = 128;
constexpr int NE = 8, IEXP = 512, ISH = 1024;
constexpr int Bn = 2, Sn = 2048, Tn = Bn * Sn;
constexpr float RESM = 0.22f;

DI float bf2f(u16 u) { union { u32 i; float f; } c; c.i = (u32)u << 16; return c.f; }
DI u16 f2bf(float f) {
  union { float f; u32 i; } c; c.f = f;
  u32 r = c.i + 0x7fffu + ((c.i >> 16) & 1u);
  return (u16)(r >> 16);
}

DI void gl2lds16(const u16* g, u16* l) {
  __builtin_amdgcn_global_load_lds((__attribute__((address_space(1))) void*)g,
                                   (__attribute__((address_space(3))) void*)l, 16, 0, 0);
}

// ---------------- fused weight conversion (all weights, one launch) ----------------
constexpr long B0 = 589824;        // wq  -> wqkv[0..)
constexpr long B1 = B0 + 196608;   // wk
constexpr long B2 = B1 + 196608;   // wv
constexpr long B3 = B2 + 589824;   // wo
constexpr long B4 = B3 + 3145728;  // wgu interleaved
constexpr long B5 = B4 + 1572864;  // wdown
constexpr long B6 = B5 + 786432;   // wshin
constexpr long B7 = B6 + 393216;   // wshout ; total 7471104 f4 = 29184 blocks

__global__ void cvt_all_k(const float4* __restrict__ wq, const float4* __restrict__ wk,
                          const float4* __restrict__ wv, const float4* __restrict__ wo,
                          const float4* __restrict__ wg, const float4* __restrict__ wu,
                          const float4* __restrict__ wd, const float4* __restrict__ wsi,
                          const float4* __restrict__ wso,
                          ushort4* __restrict__ qkvb, ushort4* __restrict__ wob,
                          ushort4* __restrict__ wgub, ushort4* __restrict__ wdnb,
                          ushort4* __restrict__ wsib, ushort4* __restrict__ wsob,
                          int* __restrict__ counts) {
  if (blockIdx.x == 0 && threadIdx.x < NE) counts[threadIdx.x] = 0;
  long i = (long)blockIdx.x * 256 + threadIdx.x;
  float4 v; ushort4* dst;
  if (i < B0) { v = wq[i]; dst = qkvb + i; }
  else if (i < B1) { v = wk[i - B0]; dst = qkvb + i; }
  else if (i < B2) { v = wv[i - B1]; dst = qkvb + i; }
  else if (i < B3) { v = wo[i - B2]; dst = wob + (i - B2); }
  else if (i < B4) {
    long k = i - B3;
    long e = k / 393216, rem = k % 393216;
    long r = rem / 384, h4 = rem % 384;
    v = (r < 512) ? wg[(e * 512 + r) * 384 + h4] : wu[(e * 512 + (r - 512)) * 384 + h4];
    dst = wgub + k;
  }
  else if (i < B5) { v = wd[i - B4]; dst = wdnb + (i - B4); }
  else if (i < B6) { v = wsi[i - B5]; dst = wsib + (i - B5); }
  else { v = wso[i - B6]; dst = wsob + (i - B6); }
  *dst = ushort4{f2bf(v.x), f2bf(v.y), f2bf(v.z), f2bf(v.w)};
}

// ---------------- elementwise / small kernels ----------------

__global__ void rmsnorm_k(const float* __restrict__ x, const float* __restrict__ w, u16* __restrict__ o) {
  __shared__ float red[4];
  long t = blockIdx.x;
  const float* row = x + t * Hdim;
  float ss = 0.f;
  for (int i = threadIdx.x; i < Hdim; i += 256) { float v = row[i]; ss += v * v; }
#pragma unroll
  for (int m = 32; m >= 1; m >>= 1) ss += __shfl_xor(ss, m);
  if ((threadIdx.x & 63) == 0) red[threadIdx.x >> 6] = ss;
  __syncthreads();
  float tot = red[0] + red[1] + red[2] + red[3];
  float sc = rsqrtf(tot * (1.f / Hdim) + 1e-6f);
  for (int i = threadIdx.x; i < Hdim; i += 256) o[t * Hdim + i] = f2bf(row[i] * sc * w[i]);
}

// qkv_raw [T,2560] -> q [B,NH,S,D]*SCALE , k [B,NKV,S,D]   (V handled by vt_k)
__global__ void rope_k(const u16* __restrict__ qkv, const int* __restrict__ pos,
                       const float* __restrict__ cosT, const float* __restrict__ sinT,
                       u16* __restrict__ qb, u16* __restrict__ kb) {
  int t = blockIdx.x;
  int b = t >> 11, s = t & 2047;
  int p = pos[t];
  const u16* row = qkv + (long)t * 2560;
  const float* cp = cosT + (long)p * Dh;
  const float* sp = sinT + (long)p * Dh;
  for (int idx = threadIdx.x; idx < NHq * Dh; idx += 256) {
    int hh = idx >> 7, d = idx & 127;
    float x = bf2f(row[idx]);
    float xr = (d < 64) ? -bf2f(row[hh * 128 + d + 64]) : bf2f(row[hh * 128 + d - 64]);
    float v = x * cp[d] + xr * sp[d];
    qb[((long)(b * NHq + hh) * Sn + s) * Dh + d] = f2bf(v * 0.0078125f); // fold SCALE=2^-7
  }
  for (int idx = threadIdx.x; idx < NKVh * Dh; idx += 256) {
    int hh = idx >> 7, d = idx & 127;
    float x = bf2f(row[1536 + idx]);
    float xr = (d < 64) ? -bf2f(row[1536 + hh * 128 + d + 64]) : bf2f(row[1536 + hh * 128 + d - 64]);
    float v = x * cp[d] + xr * sp[d];
    kb[((long)(b * NKVh + hh) * Sn + s) * Dh + d] = f2bf(v);
  }
}

// transpose V out of qkvraw: vT[b][hk][d][s] = qkvraw[b*Sn+s][2048 + hk*128 + d]
__global__ void vt_k(const u16* __restrict__ qkv, u16* __restrict__ vt) {
  __shared__ __align__(16) u16 tile[64][72];
  const int s0 = blockIdx.x * 64, d0 = blockIdx.y * 64, bh = blockIdx.z;
  const int b = bh >> 2, hk = bh & 3;
  const int tid = threadIdx.x;
#pragma unroll
  for (int ph = 0; ph < 2; ph++) {
    int e = ph * 256 + tid;
    int r = e >> 3, c = e & 7;
    uint4 v = *(const uint4*)(qkv + (long)(b * Sn + s0 + r) * 2560 + 2048 + hk * 128 + d0 + c * 8);
    *(uint4*)&tile[r][c * 8] = v;
  }
  __syncthreads();
#pragma unroll
  for (int ph = 0; ph < 2; ph++) {
    int e = ph * 256 + tid;
    int rr = e >> 3, cc = e & 7;
    union { uint4 v; u16 s[8]; } tmp;
#pragma unroll
    for (int i = 0; i < 8; i++) tmp.s[i] = tile[cc * 8 + i][rr];
    *(uint4*)(vt + ((long)(bh * Dh) + d0 + rr) * Sn + s0 + cc * 8) = tmp.v;
  }
}

// fp32 router: recompute rmsnorm from hidden2 (fp32) to match reference logits exactly
__global__ void router_k(const float* __restrict__ hid2, const float* __restrict__ ln2,
                         const float* __restrict__ rw,
                         int* __restrict__ tidx, float* __restrict__ tw, int* __restrict__ counts) {
  int wid = threadIdx.x >> 6, lane = threadIdx.x & 63;
  long t = (long)blockIdx.x * 4 + wid;
  const float* x = hid2 + t * Hdim;
  float xv[24];
  float ss = 0.f;
#pragma unroll
  for (int i = 0; i < 24; i++) { float v = x[lane + i * 64]; xv[i] = v; ss += v * v; }
#pragma unroll
  for (int m = 32; m >= 1; m >>= 1) ss += __shfl_xor(ss, m);
  float sc = rsqrtf(ss * (1.f / Hdim) + 1e-6f);
#pragma unroll
  for (int i = 0; i < 24; i++) xv[i] = xv[i] * sc * ln2[lane + i * 64];
  float lg[8];
  for (int e = 0; e < 8; e++) {
    const float* wrow = rw + e * Hdim;
    float s = 0.f;
#pragma unroll
    for (int i = 0; i < 24; i++) s += xv[i] * wrow[lane + i * 64];
#pragma unroll
    for (int m = 32; m >= 1; m >>= 1) s += __shfl_xor(s, m);
    lg[e] = s;
  }
  if (lane == 0) {
    int i0 = 0; float b0 = lg[0];
    for (int e = 1; e < 8; e++) if (lg[e] > b0) { b0 = lg[e]; i0 = e; }
    int i1 = -1; float b1 = -3e38f;
    for (int e = 0; e < 8; e++) if (e != i0 && lg[e] > b1) { b1 = lg[e]; i1 = e; }
    float w1 = 1.f / (1.f + __expf(b0 - b1));
    float w0 = 1.f - w1;
    tidx[2 * t] = i0; tidx[2 * t + 1] = i1;
    tw[2 * t] = w0; tw[2 * t + 1] = w1;
    atomicAdd(&counts[i0], 1);
    atomicAdd(&counts[i1], 1);
  }
}

__global__ void scan_k(const int* __restrict__ counts, int* __restrict__ seg, int* __restrict__ cursor) {
  if (threadIdx.x == 0 && blockIdx.x == 0) {
    int acc = 0;
    for (int e = 0; e < NE; e++) { seg[e] = acc; cursor[e] = acc; acc += counts[e]; }
  }
}

__global__ void scatter_k(const int* __restrict__ tidx, const float* __restrict__ tw,
                          int* __restrict__ cursor, int* __restrict__ perm,
                          float* __restrict__ slotw, int* __restrict__ tokslot) {
  int t = blockIdx.x * 256 + threadIdx.x;
  if (t >= Tn) return;
  for (int k = 0; k < 2; k++) {
    int e = tidx[2 * t + k];
    int p = atomicAdd(&cursor[e], 1);
    perm[p] = t;
    slotw[p] = tw[2 * t + k];
    tokslot[2 * t + k] = p;
  }
}

__global__ void act_moe_k(const u16* __restrict__ gu, const float* __restrict__ slotw,
                          u16* __restrict__ act) {
  long i8 = (long)blockIdx.x * 256 + threadIdx.x;  // 8 elems per thread
  if (i8 >= (long)2 * Tn * IEXP / 8) return;
  long slot = i8 / 64; int c8 = (int)(i8 % 64);
  union { uint4 v; u16 s[8]; } gv, uv, ov;
  gv.v = *(const uint4*)(gu + slot * 1024 + c8 * 8);
  uv.v = *(const uint4*)(gu + slot * 1024 + 512 + c8 * 8);
  float sw = slotw[slot];
#pragma unroll
  for (int k = 0; k < 8; k++) {
    float g = bf2f(gv.s[k]), u = bf2f(uv.s[k]);
    ov.s[k] = f2bf((g / (1.f + __expf(-g))) * u * sw);
  }
  *(uint4*)(act + i8 * 8) = ov.v;
}

__global__ void act_sh_k(const u16* __restrict__ shr, u16* __restrict__ act) {
  long i8 = (long)blockIdx.x * 256 + threadIdx.x;
  if (i8 >= (long)Tn * ISH / 8) return;
  long t = i8 / 128; int c8 = (int)(i8 % 128);
  union { uint4 v; u16 s[8]; } av, bv, ov;
  av.v = *(const uint4*)(shr + t * 2048 + c8 * 8);
  bv.v = *(const uint4*)(shr + t * 2048 + 1024 + c8 * 8);
#pragma unroll
  for (int k = 0; k < 8; k++) {
    float a = bf2f(av.s[k]), b = bf2f(bv.s[k]);
    ov.s[k] = f2bf((a / (1.f + __expf(-a))) * b);
  }
  *(uint4*)(act + i8 * 8) = ov.v;
}

__global__ void final_k(const float* __restrict__ hidden2, const u16* __restrict__ shy,
                        const u16* __restrict__ Y, const int* __restrict__ tokslot,
                        float* __restrict__ out) {
  long i4 = (long)blockIdx.x * 256 + threadIdx.x;  // 4 elems per thread
  if (i4 >= (long)Tn * Hdim / 4) return;
  long t = i4 / 384; int h4 = (int)(i4 % 384);
  long s0 = tokslot[2 * t], s1 = tokslot[2 * t + 1];
  float4 hv = *(const float4*)(hidden2 + i4 * 4);
  ushort4 sv = *(const ushort4*)(shy + i4 * 4);
  ushort4 y0 = *(const ushort4*)(Y + s0 * Hdim + h4 * 4);
  ushort4 y1 = *(const ushort4*)(Y + s1 * Hdim + h4 * 4);
  float4 r;
  r.x = hv.x + (bf2f(sv.x) + bf2f(y0.x) + bf2f(y1.x)) * RESM;
  r.y = hv.y + (bf2f(sv.y) + bf2f(y0.y) + bf2f(y1.y)) * RESM;
  r.z = hv.z + (bf2f(sv.z) + bf2f(y0.z) + bf2f(y1.z)) * RESM;
  r.w = hv.w + (bf2f(sv.w) + bf2f(y0.w) + bf2f(y1.w)) * RESM;
  *(float4*)(out + i4 * 4) = r;
}

// ---------------- GEMM: C[M,N] = A[M,K] @ B[N,K]^T (bf16 in, fp32 acc) ----------------
// Epilogue repacks acc through LDS (dead As/Bs) and stores uint4/float4 full rows —
// scattered scalar stores are 3-10x write-amplified at HBM (measured flash5: 377MB vs 37MB).
template <int EPI>
__global__ __launch_bounds__(256) void gemm_bt(
    const u16* __restrict__ A, const u16* __restrict__ Bb,
    float* __restrict__ Cf, u16* __restrict__ Cb, const float* __restrict__ res,
    const int* __restrict__ perm, const int* __restrict__ counts, const int* __restrict__ segoff,
    int M, int N, int K, long bstride) {
  __shared__ __align__(16) u16 smem[8448];   // As[4096] | Bs[4096]; epilogue stage [64][132]
  u16* As = smem;
  u16* Bs = smem + 4096;
  const int e = blockIdx.z;
  const u16* Bp = Bb + (long)e * bstride;
  const int meff = counts ? counts[e] : M;
  const int base = segoff ? segoff[e] : 0;
  const int m0 = blockIdx.y * 128;
  if (m0 >= meff) return;
  const int n0 = blockIdx.x * 128;
  const int tid = threadIdx.x;
  const int lane = tid & 63, wid = tid >> 6;
  const int l15 = lane & 15, quad = lane >> 4;
  const int wm = wid & 1, wn = wid >> 1;

  const int r0 = tid >> 2, c0 = (tid & 3) * 8;
  int g0 = m0 + r0; if (g0 >= meff) g0 = meff - 1;
  int g1 = m0 + r0 + 64; if (g1 >= meff) g1 = meff - 1;
  const long arow0 = perm ? (long)perm[base + g0] : (long)(base + g0);
  const long arow1 = perm ? (long)perm[base + g1] : (long)(base + g1);
  const long brow0 = n0 + r0, brow1 = n0 + r0 + 64;

  f32x4 acc[4][4];
#pragma unroll
  for (int i = 0; i < 4; i++)
#pragma unroll
    for (int j = 0; j < 4; j++) acc[i][j] = f32x4{0.f, 0.f, 0.f, 0.f};

  for (int k0 = 0; k0 < K; k0 += 32) {
    __syncthreads();
    gl2lds16(A + arow0 * K + k0 + c0, &As[tid * 8]);
    gl2lds16(A + arow1 * K + k0 + c0, &As[(tid + 256) * 8]);
    gl2lds16(Bp + brow0 * K + k0 + c0, &Bs[tid * 8]);
    gl2lds16(Bp + brow1 * K + k0 + c0, &Bs[(tid + 256) * 8]);
    __syncthreads();
    bf16x8 af[4], bfr[4];
#pragma unroll
    for (int i = 0; i < 4; i++) af[i] = *(const bf16x8*)&As[(wm * 64 + i * 16 + l15) * 32 + quad * 8];
#pragma unroll
    for (int j = 0; j < 4; j++) bfr[j] = *(const bf16x8*)&Bs[(wn * 64 + j * 16 + l15) * 32 + quad * 8];
#pragma unroll
    for (int i = 0; i < 4; i++)
#pragma unroll
      for (int j = 0; j < 4; j++)
        acc[i][j] = __builtin_amdgcn_mfma_f32_16x16x32_bf16(af[i], bfr[j], acc[i][j], 0, 0, 0);
  }

  __syncthreads();  // As/Bs dead; reuse as epilogue staging
  if (EPI == 0) {
    // bf16 out: two halves (rows wm*64..), stage [64][132], coalesced uint4 stores
    u16* sT = smem;
#pragma unroll
    for (int half = 0; half < 2; half++) {
      if (wm == half) {
#pragma unroll
        for (int i = 0; i < 4; i++)
#pragma unroll
          for (int j = 0; j < 4; j++)
#pragma unroll
            for (int r = 0; r < 4; r++)
              sT[(i * 16 + quad * 4 + r) * 132 + wn * 64 + j * 16 + l15] = f2bf(acc[i][j][r]);
      }
      __syncthreads();
#pragma unroll
      for (int rep = 0; rep < 4; rep++) {
        int lr = rep * 16 + (tid >> 4);
        int gm = m0 + half * 64 + lr;
        if (gm < meff) {
          int ch = (tid & 15) * 8;
          uint4 v = *(const uint4*)&sT[lr * 132 + ch];
          *(uint4*)(Cb + (long)(base + gm) * N + n0 + ch) = v;
        }
      }
      __syncthreads();
    }
  } else {
    // fp32 out with residual: four phases of 32 rows, stage f32 [32][132]
    float* sF = (float*)smem;
#pragma unroll
    for (int ph = 0; ph < 4; ph++) {
      if (wm == (ph >> 1)) {
#pragma unroll
        for (int ii = 0; ii < 2; ii++) {
          int i = (ph & 1) * 2 + ii;
#pragma unroll
          for (int j = 0; j < 4; j++)
#pragma unroll
            for (int r = 0; r < 4; r++)
              sF[(ii * 16 + quad * 4 + r) * 132 + wn * 64 + j * 16 + l15] = acc[i][j][r];
        }
      }
      __syncthreads();
#pragma unroll
      for (int rep = 0; rep < 2; rep++) {
        int lr = rep * 16 + (tid >> 4);
        int gm = m0 + ph * 32 + lr;
        if (gm < meff) {
          int ch = (tid & 15) * 8;  // 8 floats
          long idx = (long)(base + gm) * N + n0 + ch;
          float4 a0 = *(const float4*)&sF[lr * 132 + ch];
          float4 a1 = *(const float4*)&sF[lr * 132 + ch + 4];
          float4 r0 = *(const float4*)&res[idx];
          float4 r1 = *(const float4*)&res[idx + 4];
          float4 o0v{r0.x + a0.x * RESM, r0.y + a0.y * RESM, r0.z + a0.z * RESM, r0.w + a0.w * RESM};
          float4 o1v{r1.x + a1.x * RESM, r1.y + a1.y * RESM, r1.z + a1.z * RESM, r1.w + a1.w * RESM};
          *(float4*)&Cf[idx] = o0v;
          *(float4*)&Cf[idx + 4] = o1v;
        }
      }
      __syncthreads();
    }
  }
}

// ---------------- flash attention v6: KV-chunk parallel + coalesced bf16 epilogue ----------------
// Decomposition identical to v5 (48 chunks/bh, 1152 blocks, LPT). Changes:
//  - qt<16 (single-chunk) blocks normalize in-register and write final attn bf16 directly
//  - split blocks (qt>=16) write bf16 partials (not fp32) to slot buffers
//  - ALL global stores repacked via LDS (dead sK) into uint4 (256B-1KB contiguous segments):
//    scattered scalar stores measured 10x write-amplified (flash5: WRITE 377MB vs 37MB nominal)
__global__ __launch_bounds__(256, 3) void flash6_k(
    const u16* __restrict__ qb, const u16* __restrict__ kb, const u16* __restrict__ vt,
    u16* __restrict__ o0, u16* __restrict__ o1,
    float* __restrict__ ls0, float* __restrict__ ls1,
    u16* __restrict__ attn) {
  __shared__ __align__(16) u16 sK[64 * 136];
  __shared__ __align__(16) u16 sV[128 * 72];
  __shared__ __align__(16) u16 sP[64 * 72];
  const int rnk = blockIdx.x / 24, bh = blockIdx.x % 24;
  int qt, c;
  if (rnk == 0) { qt = 15; c = 0; }
  else if (rnk <= 16) { qt = 15 + rnk; c = 0; }
  else if (rnk == 17) { qt = 31; c = 1; }
  else {
    int p = (rnk - 18) >> 1, len = 15 - p;
    if (((rnk - 18) & 1) == 0) { qt = len - 1; c = 0; }
    else { qt = 15 + len; c = 1; }
  }
  const int kt0 = c << 4;
  const int tc = (c == 0) ? (qt < 16 ? qt + 1 : 16) : qt - 15;
  const int b = bh / 12, h = bh % 12, hk = h / 3;
  const int q0 = qt * 64;
  const u16* Q = qb + (long)(b * NHq + h) * Sn * Dh;
  const u16* Kp = kb + (long)(b * NKVh + hk) * Sn * Dh;
  const u16* Vp = vt + (long)(b * NKVh + hk) * Dh * Sn;  // [d][s]
  const int tid = threadIdx.x, lane = tid & 63, wid = tid >> 6;
  const int l15 = lane & 15, quad = lane >> 4;

  // loop-invariant Q fragments (wave wid owns rows wid*16..wid*16+15)
  bf16x8 qf[4];
  {
    const u16* qr = Q + (long)(q0 + wid * 16 + l15) * Dh + quad * 8;
#pragma unroll
    for (int ks = 0; ks < 4; ks++) qf[ks] = *(const bf16x8*)(qr + ks * 32);
  }

  // staging decomposition (4 uint4 per thread per tensor)
  int kr[4], kc[4], vr[4], vc[4];
#pragma unroll
  for (int l = 0; l < 4; l++) {
    int cc = l * 256 + tid;
    kr[l] = (cc >> 2) & 63;  kc[l] = (cc >> 8) * 32 + (cc & 3) * 8;
    vr[l] = (cc >> 2) & 127; vc[l] = (cc >> 9) * 32 + (cc & 3) * 8;
  }
  uint4 pk[4], pv[4];
#pragma unroll
  for (int l = 0; l < 4; l++) {
    pk[l] = *(const uint4*)(Kp + (long)(kt0 * 64 + kr[l]) * Dh + kc[l]);
    pv[l] = *(const uint4*)(Vp + (long)vr[l] * Sn + kt0 * 64 + vc[l]);
  }

  f32x4 o[8];
#pragma unroll
  for (int i = 0; i < 8; i++) o[i] = f32x4{0.f, 0.f, 0.f, 0.f};
  float lsum[4] = {0.f, 0.f, 0.f, 0.f};

  for (int j = 0; j < tc; j++) {
    const int kt = kt0 + j;
    __syncthreads();
#pragma unroll
    for (int l = 0; l < 4; l++) *(uint4*)&sK[kr[l] * 136 + kc[l]] = pk[l];
#pragma unroll
    for (int l = 0; l < 4; l++) *(uint4*)&sV[vr[l] * 72 + vc[l]] = pv[l];
    if (j + 1 < tc) {
      int kn = (kt + 1) * 64;
#pragma unroll
      for (int l = 0; l < 4; l++) {
        pk[l] = *(const uint4*)(Kp + (long)(kn + kr[l]) * Dh + kc[l]);
        pv[l] = *(const uint4*)(Vp + (long)vr[l] * Sn + kn + vc[l]);
      }
    }
    __syncthreads();

    // S = Q K^T
    f32x4 sv[4];
#pragma unroll
    for (int nt = 0; nt < 4; nt++) sv[nt] = f32x4{0.f, 0.f, 0.f, 0.f};
#pragma unroll
    for (int ks = 0; ks < 4; ks++)
#pragma unroll
      for (int nt = 0; nt < 4; nt++) {
        bf16x8 bk = *(const bf16x8*)&sK[(nt * 16 + l15) * 136 + ks * 32 + quad * 8];
        sv[nt] = __builtin_amdgcn_mfma_f32_16x16x32_bf16(qf[ks], bk, sv[nt], 0, 0, 0);
      }
    // causal mask only on the diagonal tile
    if (kt == qt) {
#pragma unroll
      for (int nt = 0; nt < 4; nt++)
#pragma unroll
        for (int r = 0; r < 4; r++) {
          int rr = q0 + wid * 16 + quad * 4 + r, cc = kt * 64 + nt * 16 + l15;
          if (cc > rr) sv[nt][r] = -1e30f;
        }
    }
    // exp -> sP (wave-private rows), accumulate lsum
#pragma unroll
    for (int nt = 0; nt < 4; nt++)
#pragma unroll
      for (int r = 0; r < 4; r++) {
        float pe = __expf(sv[nt][r]);
        lsum[r] += pe;
        sP[(wid * 16 + quad * 4 + r) * 72 + nt * 16 + l15] = f2bf(pe);
      }
    // O += P V
#pragma unroll
    for (int ks = 0; ks < 2; ks++) {
      bf16x8 pa = *(const bf16x8*)&sP[(wid * 16 + l15) * 72 + ks * 32 + quad * 8];
#pragma unroll
      for (int dt = 0; dt < 8; dt++) {
        bf16x8 vv = *(const bf16x8*)&sV[(ks * 128 + dt * 16 + l15) * 72 / 128 == 0 ? (dt * 16 + l15) * 72 + ks * 32 + quad * 8 : (dt * 16 + l15) * 72 + ks * 32 + quad * 8];
        o[dt] = __builtin_amdgcn_mfma_f32_16x16x32_bf16(pa, vv, o[dt], 0, 0, 0);
      }
    }
  }

  // ---- epilogue: reduce sums, repack via LDS (sK dead), coalesced uint4 stores ----
  __syncthreads();  // all waves done reading sK/sV/sP
  float rs[4];
#pragma unroll
  for (int r = 0; r < 4; r++) {
    float t = lsum[r];
    t += __shfl_xor(t, 1); t += __shfl_xor(t, 2); t += __shfl_xor(t, 4); t += __shfl_xor(t, 8);
    rs[r] = t;
  }
  const bool direct = (c == 0) && (qt < 16);
  u16* sT = sK;  // [64][132]
  float inv4[4];
#pragma unroll
  for (int r = 0; r < 4; r++) inv4[r] = direct ? 1.f / rs[r] : 1.f;
#pragma unroll
  for (int dt = 0; dt < 8; dt++)
#pragma unroll
    for (int r = 0; r < 4; r++)
      sT[(wid * 16 + quad * 4 + r) * 132 + dt * 16 + l15] = f2bf(o[dt][r] * inv4[r]);

  if (direct) {
#pragma unroll
    for (int rep = 0; rep < 4; rep++) {
      int row = wid * 16 + rep * 4 + quad;
      uint4 v = *(const uint4*)&sT[row * 132 + l15 * 8];
      *(uint4*)(attn + ((long)(b * Sn + q0 + row)) * (long)Hdim + h * Dh + l15 * 8) = v;
    }
  } else {
    u16* op = (c == 0 ? o0 : o1) + ((long)bh * Sn + q0) * Dh;
    float* lp = (c == 0 ? ls0 : ls1) + (long)bh * Sn + q0;
#pragma unroll
    for (int rep = 0; rep < 4; rep++) {
      int row = wid * 16 + rep * 4 + quad;
      uint4 v = *(const uint4*)&sT[row * 132 + l15 * 8];
      *(uint4*)(op + (long)row * Dh + l15 * 8) = v;
    }
    if (l15 == 0) {
#pragma unroll
      for (int r = 0; r < 4; r++) lp[wid * 16 + quad * 4 + r] = rs[r];
    }
  }
}

// combine bf16 chunk partials for rows 1024..2047, normalize, emit attn bf16 (coalesced)
__global__ void attn_norm6_k(const u16* __restrict__ o0, const u16* __restrict__ o1,
                             const float* __restrict__ l0, const float* __restrict__ l1,
                             u16* __restrict__ attn) {
  const int gid = blockIdx.x;  // 24 bh * 64 row-groups of 16
  const int bh = gid >> 6, rb = gid & 63;
  const int row = 1024 + rb * 16 + (threadIdx.x >> 4);
  const int ch = (threadIdx.x & 15) * 8;
  const long idx = ((long)bh * Sn + row) * Dh + ch;
  union { uint4 v; u16 s[8]; } a, b2, ov;
  a.v = *(const uint4*)(o0 + idx);
  b2.v = *(const uint4*)(o1 + idx);
  const float inv = 1.f / (l0[(long)bh * Sn + row] + l1[(long)bh * Sn + row]);
#pragma unroll
  for (int k = 0; k < 8; k++) ov.s[k] = f2bf((bf2f(a.s[k]) + bf2f(b2.s[k])) * inv);
  const int b = bh / 12, h = bh % 12;
  *(uint4*)(attn + ((long)(b * Sn + row)) * (long)Hdim + h * Dh + ch) = ov.v;
}

// ---------------- host ----------------

extern "C" void kernel_launch(void* const* d_in, const int* in_sizes, int n_in,
                              void* d_out, int out_size, void* d_ws, size_t ws_size,
                              hipStream_t stream) {
  const float* hidden = (const float*)d_in[0];
  const int* pos = (const int*)d_in[1];
  const float* cosT = (const float*)d_in[2];
  const float* sinT = (const float*)d_in[3];
  const float* ln1 = (const float*)d_in[4];
  const float* ln2 = (const float*)d_in[5];
  const float* wq = (const float*)d_in[6];
  const float* wk = (const float*)d_in[7];
  const float* wv = (const float*)d_in[8];
  const float* wo = (const float*)d_in[9];
  const float* router_w = (const float*)d_in[10];
  const float* w_gate = (const float*)d_in[11];
  const float* w_up = (const float*)d_in[12];
  const float* w_down = (const float*)d_in[13];
  const float* shared_in = (const float*)d_in[14];
  const float* shared_out = (const float*)d_in[15];
  float* out = (float*)d_out;

  // ---- workspace layout with phase-based aliasing ----
  char* p = (char*)d_ws;
  auto alloc = [&](size_t bytes) -> char* {
    char* r = p; p += (bytes + 255) & ~(size_t)255; return r;
  };
  u16* wqkv_b = (u16*)alloc((size_t)2560 * Hdim * 2);
  u16* wo_b = (u16*)alloc((size_t)Hdim * Hdim * 2);
  u16* wgu_b = (u16*)alloc((size_t)NE * 1024 * Hdim * 2);
  u16* wdown_b = (u16*)alloc((size_t)NE * Hdim * IEXP * 2);
  u16* wshin_b = (u16*)alloc((size_t)2048 * Hdim * 2);
  u16* wshout_b = (u16*)alloc((size_t)Hdim * ISH * 2);
  char* regH = alloc((size_t)Tn * Hdim * 4);                // x1n | attn-partial slot0 | hidden2
  char* reg1 = alloc((size_t)Tn * 2560 * 2);                // qkvraw | attn | gu | shraw
  char* reg2 = alloc((size_t)Bn * NHq * Sn * Dh * 2);       // qbuf | x2n | shy
  char* reg3 = alloc((size_t)2 * Bn * NKVh * Sn * Dh * 2);  // kbuf+vT | act | shact
  u16* Y_b = (u16*)alloc((size_t)2 * Tn * Hdim * 2);        // also attn-partial slot1
  int* tidx = (int*)alloc(Tn * 2 * 4);
  float* tw = (float*)alloc(Tn * 2 * 4);
  int* tokslot = (int*)alloc(Tn * 2 * 4);
  int* perm = (int*)alloc(Tn * 2 * 4);
  float* slotw = (float*)alloc(Tn * 2 * 4);
  int* counts = (int*)alloc(64);
  int* seg = (int*)alloc(64);
  int* cursor = (int*)alloc(64);
  float* lsum0 = (float*)alloc((size_t)24 * Sn * 4);
  float* lsum1 = (float*)alloc((size_t)24 * Sn * 4);

  u16* x1n = (u16*)regH;
  float* hidden2 = (float*)regH;
  u16* opart0 = (u16*)regH;  // bf16 partials, upper-half rows only; free during attention
  u16* opart1 = (u16*)Y_b;   // Y written later
  u16* qkvraw = (u16*)reg1;
  u16* attn = (u16*)reg1;
  u16* gu_b = (u16*)reg1;
  u16* shraw_b = (u16*)reg1;
  u16* qbuf = (u16*)reg2;
  u16* x2n = (u16*)reg2;
  u16* shy_b = (u16*)reg2;
  u16* kbuf = (u16*)reg3;
  u16* vtbuf = kbuf + (size_t)Bn * NKVh * Sn * Dh;  // transposed V [b][hk][d][s]
  u16* act_b = (u16*)reg3;
  u16* shact_b = (u16*)reg3;

  auto cdiv = [](long a, long b) { return (int)((a + b - 1) / b); };

  // fused weight conversion (+ counts zeroing)
  cvt_all_k<<<(int)(B7 / 256), 256, 0, stream>>>(
      (const float4*)wq, (const float4*)wk, (const float4*)wv, (const float4*)wo,
      (const float4*)w_gate, (const float4*)w_up, (const float4*)w_down,
      (const float4*)shared_in, (const float4*)shared_out,
      (ushort4*)wqkv_b, (ushort4*)wo_b, (ushort4*)wgu_b, (ushort4*)wdown_b,
      (ushort4*)wshin_b, (ushort4*)wshout_b, counts);

  // attention block
  rmsnorm_k<<<Tn, 256, 0, stream>>>(hidden, ln1, x1n);
  gemm_bt<0><<<dim3(2560 / 128, Tn / 128, 1), 256, 0, stream>>>(
      x1n, wqkv_b, nullptr, qkvraw, nullptr, nullptr, nullptr, nullptr, Tn, 2560, Hdim, 0);
  rope_k<<<Tn, 256, 0, stream>>>(qkvraw, pos, cosT, sinT, qbuf, kbuf);
  vt_k<<<dim3(Sn / 64, Dh / 64, Bn * NKVh), 256, 0, stream>>>(qkvraw, vtbuf);
  flash6_k<<<dim3(1152, 1, 1), 256, 0, stream>>>(qbuf, kbuf, vtbuf, opart0, opart1, lsum0, lsum1, attn);
  attn_norm6_k<<<dim3(24 * 64, 1, 1), 256, 0, stream>>>(opart0, opart1, lsum0, lsum1, attn);
  gemm_bt<2><<<dim3(Hdim / 128, Tn / 128, 1), 256, 0, stream>>>(
      attn, wo_b, hidden2, nullptr, hidden, nullptr, nullptr, nullptr, Tn, Hdim, Hdim, 0);

  // MoE block
  rmsnorm_k<<<Tn, 256, 0, stream>>>(hidden2, ln2, x2n);
  router_k<<<Tn / 4, 256, 0, stream>>>(hidden2, ln2, router_w, tidx, tw, counts);
  scan_k<<<1, 64, 0, stream>>>(counts, seg, cursor);
  scatter_k<<<cdiv(Tn, 256), 256, 0, stream>>>(tidx, tw, cursor, perm, slotw, tokslot);
  gemm_bt<0><<<dim3(1024 / 128, Tn / 128, NE), 256, 0, stream>>>(
      x2n, wgu_b, nullptr, gu_b, nullptr, perm, counts, seg, 0, 1024, Hdim, (long)1024 * Hdim);
  act_moe_k<<<cdiv((long)2 * Tn * IEXP / 8, 256), 256, 0, stream>>>(gu_b, slotw, act_b);
  gemm_bt<0><<<dim3(Hdim / 128, Tn / 128, NE), 256, 0, stream>>>(
      act_b, wdown_b, nullptr, Y_b, nullptr, nullptr, counts, seg, 0, Hdim, IEXP, (long)Hdim * IEXP);

  // shared MLP
  gemm_bt<0><<<dim3(2048 / 128, Tn / 128, 1), 256, 0, stream>>>(
      x2n, wshin_b, nullptr, shraw_b, nullptr, nullptr, nullptr, nullptr, Tn, 2048, Hdim, 0);
  act_sh_k<<<cdiv((long)Tn * ISH / 8, 256), 256, 0, stream>>>(shraw_b, shact_b);
  gemm_bt<0><<<dim3(Hdim / 128, Tn / 128, 1), 256, 0, stream>>>(
      shact_b, wshout_b, nullptr, shy_b, nullptr, nullptr, nullptr, nullptr, Tn, Hdim, ISH, 0);

  // combine
  final_k<<<cdiv((long)Tn * Hdim / 4, 256), 256, 0, stream>>>(hidden2, shy_b, Y_b, tokslot, out);
}

// Round 4
// 695.911 us; speedup vs baseline: 1.1300x; 1.1300x over previous
//
#include <hip/hip_runtime.h>
#include <cstdint>
#include <cstddef>

using u16 = unsigned short;
using u32 = unsigned int;

typedef __bf16 bf16x8 __attribute__((ext_vector_type(8)));
typedef float  f32x4  __attribute__((ext_vector_type(4)));

#define DI __device__ __forceinline__

constexpr int Hdim = 1536;
constexpr int NHq = 12, NKVh = 4, Dh = 128;
constexpr int NE = 8, IEXP = 512, ISH = 1024;
constexpr int Bn = 2, Sn = 2048, Tn = Bn * Sn;
constexpr float RESM = 0.22f;

DI float bf2f(u16 u) { union { u32 i; float f; } c; c.i = (u32)u << 16; return c.f; }
DI u16 f2bf(float f) {
  union { float f; u32 i; } c; c.f = f;
  u32 r = c.i + 0x7fffu + ((c.i >> 16) & 1u);
  return (u16)(r >> 16);
}

DI void gl2lds16(const u16* g, u16* l) {
  __builtin_amdgcn_global_load_lds((__attribute__((address_space(1))) void*)g,
                                   (__attribute__((address_space(3))) void*)l, 16, 0, 0);
}

// flash7 LPT rank tables: (qt2, chunk) sorted by descending tile count.
// qt2<=7: single chunk (tiles 0..2qt2+1). qt2>=8: chunkA tiles 0..15, chunkB tiles 16..2qt2+1.
__constant__ signed char c_qt2[24] = {7,8,9,10,11,12,13,14,15,15,6,14,5,13,4,12,3,11,2,10,1,9,0,8};
__constant__ signed char c_ch[24]  = {0,0,0,0,0,0,0,0,0,1, 0,1, 0,1, 0,1, 0,1, 0,1, 0,1, 0,1};

// ---------------- fused weight conversion (all weights, one launch) ----------------
constexpr long B0 = 589824;        // wq  -> wqkv[0..)
constexpr long B1 = B0 + 196608;   // wk
constexpr long B2 = B1 + 196608;   // wv
constexpr long B3 = B2 + 589824;   // wo
constexpr long B4 = B3 + 3145728;  // wgu interleaved
constexpr long B5 = B4 + 1572864;  // wdown
constexpr long B6 = B5 + 786432;   // wshin
constexpr long B7 = B6 + 393216;   // wshout ; total 7471104 f4 = 29184 blocks

__global__ void cvt_all_k(const float4* __restrict__ wq, const float4* __restrict__ wk,
                          const float4* __restrict__ wv, const float4* __restrict__ wo,
                          const float4* __restrict__ wg, const float4* __restrict__ wu,
                          const float4* __restrict__ wd, const float4* __restrict__ wsi,
                          const float4* __restrict__ wso,
                          ushort4* __restrict__ qkvb, ushort4* __restrict__ wob,
                          ushort4* __restrict__ wgub, ushort4* __restrict__ wdnb,
                          ushort4* __restrict__ wsib, ushort4* __restrict__ wsob,
                          int* __restrict__ counts) {
  if (blockIdx.x == 0 && threadIdx.x < NE) counts[threadIdx.x] = 0;
  long i = (long)blockIdx.x * 256 + threadIdx.x;
  float4 v; ushort4* dst;
  if (i < B0) { v = wq[i]; dst = qkvb + i; }
  else if (i < B1) { v = wk[i - B0]; dst = qkvb + i; }
  else if (i < B2) { v = wv[i - B1]; dst = qkvb + i; }
  else if (i < B3) { v = wo[i - B2]; dst = wob + (i - B2); }
  else if (i < B4) {
    long k = i - B3;
    long e = k / 393216, rem = k % 393216;
    long r = rem / 384, h4 = rem % 384;
    v = (r < 512) ? wg[(e * 512 + r) * 384 + h4] : wu[(e * 512 + (r - 512)) * 384 + h4];
    dst = wgub + k;
  }
  else if (i < B5) { v = wd[i - B4]; dst = wdnb + (i - B4); }
  else if (i < B6) { v = wsi[i - B5]; dst = wsib + (i - B5); }
  else { v = wso[i - B6]; dst = wsob + (i - B6); }
  *dst = ushort4{f2bf(v.x), f2bf(v.y), f2bf(v.z), f2bf(v.w)};
}

// ---------------- elementwise / small kernels ----------------

__global__ void rmsnorm_k(const float* __restrict__ x, const float* __restrict__ w, u16* __restrict__ o) {
  __shared__ float red[4];
  long t = blockIdx.x;
  const float* row = x + t * Hdim;
  float ss = 0.f;
  for (int i = threadIdx.x; i < Hdim; i += 256) { float v = row[i]; ss += v * v; }
#pragma unroll
  for (int m = 32; m >= 1; m >>= 1) ss += __shfl_xor(ss, m);
  if ((threadIdx.x & 63) == 0) red[threadIdx.x >> 6] = ss;
  __syncthreads();
  float tot = red[0] + red[1] + red[2] + red[3];
  float sc = rsqrtf(tot * (1.f / Hdim) + 1e-6f);
  for (int i = threadIdx.x; i < Hdim; i += 256) o[t * Hdim + i] = f2bf(row[i] * sc * w[i]);
}

// qkv_raw [T,2560] -> q [B,NH,S,D]*SCALE , k [B,NKV,S,D]   (V handled by vt_k)
__global__ void rope_k(const u16* __restrict__ qkv, const int* __restrict__ pos,
                       const float* __restrict__ cosT, const float* __restrict__ sinT,
                       u16* __restrict__ qb, u16* __restrict__ kb) {
  int t = blockIdx.x;
  int b = t >> 11, s = t & 2047;
  int p = pos[t];
  const u16* row = qkv + (long)t * 2560;
  const float* cp = cosT + (long)p * Dh;
  const float* sp = sinT + (long)p * Dh;
  for (int idx = threadIdx.x; idx < NHq * Dh; idx += 256) {
    int hh = idx >> 7, d = idx & 127;
    float x = bf2f(row[idx]);
    float xr = (d < 64) ? -bf2f(row[hh * 128 + d + 64]) : bf2f(row[hh * 128 + d - 64]);
    float v = x * cp[d] + xr * sp[d];
    qb[((long)(b * NHq + hh) * Sn + s) * Dh + d] = f2bf(v * 0.0078125f); // fold SCALE=2^-7
  }
  for (int idx = threadIdx.x; idx < NKVh * Dh; idx += 256) {
    int hh = idx >> 7, d = idx & 127;
    float x = bf2f(row[1536 + idx]);
    float xr = (d < 64) ? -bf2f(row[1536 + hh * 128 + d + 64]) : bf2f(row[1536 + hh * 128 + d - 64]);
    float v = x * cp[d] + xr * sp[d];
    kb[((long)(b * NKVh + hh) * Sn + s) * Dh + d] = f2bf(v);
  }
}

// transpose V out of qkvraw: vT[b][hk][d][s] = qkvraw[b*Sn+s][2048 + hk*128 + d]
__global__ void vt_k(const u16* __restrict__ qkv, u16* __restrict__ vt) {
  __shared__ __align__(16) u16 tile[64][72];
  const int s0 = blockIdx.x * 64, d0 = blockIdx.y * 64, bh = blockIdx.z;
  const int b = bh >> 2, hk = bh & 3;
  const int tid = threadIdx.x;
#pragma unroll
  for (int ph = 0; ph < 2; ph++) {
    int e = ph * 256 + tid;
    int r = e >> 3, c = e & 7;
    uint4 v = *(const uint4*)(qkv + (long)(b * Sn + s0 + r) * 2560 + 2048 + hk * 128 + d0 + c * 8);
    *(uint4*)&tile[r][c * 8] = v;
  }
  __syncthreads();
#pragma unroll
  for (int ph = 0; ph < 2; ph++) {
    int e = ph * 256 + tid;
    int rr = e >> 3, cc = e & 7;
    union { uint4 v; u16 s[8]; } tmp;
#pragma unroll
    for (int i = 0; i < 8; i++) tmp.s[i] = tile[cc * 8 + i][rr];
    *(uint4*)(vt + ((long)(bh * Dh) + d0 + rr) * Sn + s0 + cc * 8) = tmp.v;
  }
}

// fp32 router: recompute rmsnorm from hidden2 (fp32) to match reference logits exactly
__global__ void router_k(const float* __restrict__ hid2, const float* __restrict__ ln2,
                         const float* __restrict__ rw,
                         int* __restrict__ tidx, float* __restrict__ tw, int* __restrict__ counts) {
  int wid = threadIdx.x >> 6, lane = threadIdx.x & 63;
  long t = (long)blockIdx.x * 4 + wid;
  const float* x = hid2 + t * Hdim;
  float xv[24];
  float ss = 0.f;
#pragma unroll
  for (int i = 0; i < 24; i++) { float v = x[lane + i * 64]; xv[i] = v; ss += v * v; }
#pragma unroll
  for (int m = 32; m >= 1; m >>= 1) ss += __shfl_xor(ss, m);
  float sc = rsqrtf(ss * (1.f / Hdim) + 1e-6f);
#pragma unroll
  for (int i = 0; i < 24; i++) xv[i] = xv[i] * sc * ln2[lane + i * 64];
  float lg[8];
  for (int e = 0; e < 8; e++) {
    const float* wrow = rw + e * Hdim;
    float s = 0.f;
#pragma unroll
    for (int i = 0; i < 24; i++) s += xv[i] * wrow[lane + i * 64];
#pragma unroll
    for (int m = 32; m >= 1; m >>= 1) s += __shfl_xor(s, m);
    lg[e] = s;
  }
  if (lane == 0) {
    int i0 = 0; float b0 = lg[0];
    for (int e = 1; e < 8; e++) if (lg[e] > b0) { b0 = lg[e]; i0 = e; }
    int i1 = -1; float b1 = -3e38f;
    for (int e = 0; e < 8; e++) if (e != i0 && lg[e] > b1) { b1 = lg[e]; i1 = e; }
    float w1 = 1.f / (1.f + __expf(b0 - b1));
    float w0 = 1.f - w1;
    tidx[2 * t] = i0; tidx[2 * t + 1] = i1;
    tw[2 * t] = w0; tw[2 * t + 1] = w1;
    atomicAdd(&counts[i0], 1);
    atomicAdd(&counts[i1], 1);
  }
}

__global__ void scan_k(const int* __restrict__ counts, int* __restrict__ seg, int* __restrict__ cursor) {
  if (threadIdx.x == 0 && blockIdx.x == 0) {
    int acc = 0;
    for (int e = 0; e < NE; e++) { seg[e] = acc; cursor[e] = acc; acc += counts[e]; }
  }
}

__global__ void scatter_k(const int* __restrict__ tidx, const float* __restrict__ tw,
                          int* __restrict__ cursor, int* __restrict__ perm,
                          float* __restrict__ slotw, int* __restrict__ tokslot) {
  int t = blockIdx.x * 256 + threadIdx.x;
  if (t >= Tn) return;
  for (int k = 0; k < 2; k++) {
    int e = tidx[2 * t + k];
    int p = atomicAdd(&cursor[e], 1);
    perm[p] = t;
    slotw[p] = tw[2 * t + k];
    tokslot[2 * t + k] = p;
  }
}

__global__ void act_moe_k(const u16* __restrict__ gu, const float* __restrict__ slotw,
                          u16* __restrict__ act) {
  long i8 = (long)blockIdx.x * 256 + threadIdx.x;  // 8 elems per thread
  if (i8 >= (long)2 * Tn * IEXP / 8) return;
  long slot = i8 / 64; int c8 = (int)(i8 % 64);
  union { uint4 v; u16 s[8]; } gv, uv, ov;
  gv.v = *(const uint4*)(gu + slot * 1024 + c8 * 8);
  uv.v = *(const uint4*)(gu + slot * 1024 + 512 + c8 * 8);
  float sw = slotw[slot];
#pragma unroll
  for (int k = 0; k < 8; k++) {
    float g = bf2f(gv.s[k]), u = bf2f(uv.s[k]);
    ov.s[k] = f2bf((g / (1.f + __expf(-g))) * u * sw);
  }
  *(uint4*)(act + i8 * 8) = ov.v;
}

__global__ void act_sh_k(const u16* __restrict__ shr, u16* __restrict__ act) {
  long i8 = (long)blockIdx.x * 256 + threadIdx.x;
  if (i8 >= (long)Tn * ISH / 8) return;
  long t = i8 / 128; int c8 = (int)(i8 % 128);
  union { uint4 v; u16 s[8]; } av, bv, ov;
  av.v = *(const uint4*)(shr + t * 2048 + c8 * 8);
  bv.v = *(const uint4*)(shr + t * 2048 + 1024 + c8 * 8);
#pragma unroll
  for (int k = 0; k < 8; k++) {
    float a = bf2f(av.s[k]), b = bf2f(bv.s[k]);
    ov.s[k] = f2bf((a / (1.f + __expf(-a))) * b);
  }
  *(uint4*)(act + i8 * 8) = ov.v;
}

__global__ void final_k(const float* __restrict__ hidden2, const u16* __restrict__ shy,
                        const u16* __restrict__ Y, const int* __restrict__ tokslot,
                        float* __restrict__ out) {
  long i4 = (long)blockIdx.x * 256 + threadIdx.x;  // 4 elems per thread
  if (i4 >= (long)Tn * Hdim / 4) return;
  long t = i4 / 384; int h4 = (int)(i4 % 384);
  long s0 = tokslot[2 * t], s1 = tokslot[2 * t + 1];
  float4 hv = *(const float4*)(hidden2 + i4 * 4);
  ushort4 sv = *(const ushort4*)(shy + i4 * 4);
  ushort4 y0 = *(const ushort4*)(Y + s0 * Hdim + h4 * 4);
  ushort4 y1 = *(const ushort4*)(Y + s1 * Hdim + h4 * 4);
  float4 r;
  r.x = hv.x + (bf2f(sv.x) + bf2f(y0.x) + bf2f(y1.x)) * RESM;
  r.y = hv.y + (bf2f(sv.y) + bf2f(y0.y) + bf2f(y1.y)) * RESM;
  r.z = hv.z + (bf2f(sv.z) + bf2f(y0.z) + bf2f(y1.z)) * RESM;
  r.w = hv.w + (bf2f(sv.w) + bf2f(y0.w) + bf2f(y1.w)) * RESM;
  *(float4*)(out + i4 * 4) = r;
}

// ---------------- GEMM: C[M,N] = A[M,K] @ B[N,K]^T (bf16 in, fp32 acc) ----------------
template <int EPI>
__global__ __launch_bounds__(256) void gemm_bt(
    const u16* __restrict__ A, const u16* __restrict__ Bb,
    float* __restrict__ Cf, u16* __restrict__ Cb, const float* __restrict__ res,
    const int* __restrict__ perm, const int* __restrict__ counts, const int* __restrict__ segoff,
    int M, int N, int K, long bstride) {
  __shared__ __align__(16) u16 smem[8448];   // As[4096] | Bs[4096]; epilogue stage [64][132]
  u16* As = smem;
  u16* Bs = smem + 4096;
  const int e = blockIdx.z;
  const u16* Bp = Bb + (long)e * bstride;
  const int meff = counts ? counts[e] : M;
  const int base = segoff ? segoff[e] : 0;
  const int m0 = blockIdx.y * 128;
  if (m0 >= meff) return;
  const int n0 = blockIdx.x * 128;
  const int tid = threadIdx.x;
  const int lane = tid & 63, wid = tid >> 6;
  const int l15 = lane & 15, quad = lane >> 4;
  const int wm = wid & 1, wn = wid >> 1;

  const int r0 = tid >> 2, c0 = (tid & 3) * 8;
  int g0 = m0 + r0; if (g0 >= meff) g0 = meff - 1;
  int g1 = m0 + r0 + 64; if (g1 >= meff) g1 = meff - 1;
  const long arow0 = perm ? (long)perm[base + g0] : (long)(base + g0);
  const long arow1 = perm ? (long)perm[base + g1] : (long)(base + g1);
  const long brow0 = n0 + r0, brow1 = n0 + r0 + 64;

  f32x4 acc[4][4];
#pragma unroll
  for (int i = 0; i < 4; i++)
#pragma unroll
    for (int j = 0; j < 4; j++) acc[i][j] = f32x4{0.f, 0.f, 0.f, 0.f};

  for (int k0 = 0; k0 < K; k0 += 32) {
    __syncthreads();
    gl2lds16(A + arow0 * K + k0 + c0, &As[tid * 8]);
    gl2lds16(A + arow1 * K + k0 + c0, &As[(tid + 256) * 8]);
    gl2lds16(Bp + brow0 * K + k0 + c0, &Bs[tid * 8]);
    gl2lds16(Bp + brow1 * K + k0 + c0, &Bs[(tid + 256) * 8]);
    __syncthreads();
    bf16x8 af[4], bfr[4];
#pragma unroll
    for (int i = 0; i < 4; i++) af[i] = *(const bf16x8*)&As[(wm * 64 + i * 16 + l15) * 32 + quad * 8];
#pragma unroll
    for (int j = 0; j < 4; j++) bfr[j] = *(const bf16x8*)&Bs[(wn * 64 + j * 16 + l15) * 32 + quad * 8];
#pragma unroll
    for (int i = 0; i < 4; i++)
#pragma unroll
      for (int j = 0; j < 4; j++)
        acc[i][j] = __builtin_amdgcn_mfma_f32_16x16x32_bf16(af[i], bfr[j], acc[i][j], 0, 0, 0);
  }

  __syncthreads();  // As/Bs dead; reuse as epilogue staging
  if (EPI == 0) {
    // bf16 out: two halves (rows wm*64..), stage [64][132], coalesced uint4 stores
    u16* sT = smem;
#pragma unroll
    for (int half = 0; half < 2; half++) {
      if (wm == half) {
#pragma unroll
        for (int i = 0; i < 4; i++)
#pragma unroll
          for (int j = 0; j < 4; j++)
#pragma unroll
            for (int r = 0; r < 4; r++)
              sT[(i * 16 + quad * 4 + r) * 132 + wn * 64 + j * 16 + l15] = f2bf(acc[i][j][r]);
      }
      __syncthreads();
#pragma unroll
      for (int rep = 0; rep < 4; rep++) {
        int lr = rep * 16 + (tid >> 4);
        int gm = m0 + half * 64 + lr;
        if (gm < meff) {
          int ch = (tid & 15) * 8;
          uint4 v = *(const uint4*)&sT[lr * 132 + ch];
          *(uint4*)(Cb + (long)(base + gm) * N + n0 + ch) = v;
        }
      }
      __syncthreads();
    }
  } else {
    // fp32 out with residual: four phases of 32 rows, stage f32 [32][132]
    float* sF = (float*)smem;
#pragma unroll
    for (int ph = 0; ph < 4; ph++) {
      if (wm == (ph >> 1)) {
#pragma unroll
        for (int ii = 0; ii < 2; ii++) {
          int i = (ph & 1) * 2 + ii;
#pragma unroll
          for (int j = 0; j < 4; j++)
#pragma unroll
            for (int r = 0; r < 4; r++)
              sF[(ii * 16 + quad * 4 + r) * 132 + wn * 64 + j * 16 + l15] = acc[i][j][r];
        }
      }
      __syncthreads();
#pragma unroll
      for (int rep = 0; rep < 2; rep++) {
        int lr = rep * 16 + (tid >> 4);
        int gm = m0 + ph * 32 + lr;
        if (gm < meff) {
          int ch = (tid & 15) * 8;  // 8 floats
          long idx = (long)(base + gm) * N + n0 + ch;
          float4 a0 = *(const float4*)&sF[lr * 132 + ch];
          float4 a1 = *(const float4*)&sF[lr * 132 + ch + 4];
          float4 r0v = *(const float4*)&res[idx];
          float4 r1v = *(const float4*)&res[idx + 4];
          float4 o0v{r0v.x + a0.x * RESM, r0v.y + a0.y * RESM, r0v.z + a0.z * RESM, r0v.w + a0.w * RESM};
          float4 o1v{r1v.x + a1.x * RESM, r1v.y + a1.y * RESM, r1v.z + a1.z * RESM, r1v.w + a1.w * RESM};
          *(float4*)&Cf[idx] = o0v;
          *(float4*)&Cf[idx + 4] = o1v;
        }
      }
      __syncthreads();
    }
  }
}

// ---------------- flash attention v7: BQ=128, gl2lds double-buffer, swizzled linear LDS ----------
// Fixes vs v6 (both 141us): (a) register "prefetch" was sunk by the VGPR cap at occupancy 3 ->
// gl2lds staging has NO register payload, so the one-iteration overlap (issue at top, drained by
// the iteration-end __syncthreads' automatic vmcnt(0)) cannot be defeated. (b) two Q-strips per
// block share each staged K/V tile -> through-L2 K/V volume halves (405->209 MB). (c) LDS must be
// linear for gl2lds: bank-decorrelation via chunk-XOR applied to the GLOBAL source AND the ds_read
// index (same involution both sides). Hybrid decomposition: qt2<=7 whole (direct out, rows<1024);
// qt2>=8 split at tile 16 (bf16 partials, combined by attn_norm6_k). 576 blocks, all <=16 iters.
__global__ __launch_bounds__(256, 2) void flash7_k(
    const u16* __restrict__ qb, const u16* __restrict__ kb, const u16* __restrict__ vt,
    u16* __restrict__ o0, u16* __restrict__ o1,
    float* __restrict__ ls0, float* __restrict__ ls1,
    u16* __restrict__ attn) {
  // sK[2][64*128] @0, sV[2][128*64] @16384, sP[64*72] @32768  (u16 units; 74752 B total)
  __shared__ __align__(16) u16 smem[37376];
  const int rnk = blockIdx.x / 24, bh = blockIdx.x % 24;
  const int qt2 = c_qt2[rnk], ch = c_ch[rnk];
  const int jmaxall = 2 * qt2 + 1;
  const int kt0 = ch ? 16 : 0;
  const int ktend = ch ? jmaxall : (jmaxall < 15 ? jmaxall : 15);
  const int tc = ktend - kt0 + 1;
  const bool split = (qt2 >= 8);
  const int b = bh / 12, h = bh % 12, hk = h / 3;
  const int q0 = qt2 * 128;
  const u16* Q = qb + (long)(b * NHq + h) * Sn * Dh;
  const u16* Kp = kb + (long)(b * NKVh + hk) * Sn * Dh;
  const u16* Vp = vt + (long)(b * NKVh + hk) * Dh * Sn;  // [d][s]
  const int tid = threadIdx.x, lane = tid & 63, wid = tid >> 6;
  const int l15 = lane & 15, quad = lane >> 4;

  // loop-invariant Q fragments for both strips (wave wid owns rows wid*16..+15 of each strip)
  bf16x8 qf[2][4];
#pragma unroll
  for (int s = 0; s < 2; s++) {
    const u16* qr = Q + (long)(q0 + s * 64 + wid * 16 + l15) * Dh + quad * 8;
#pragma unroll
    for (int ks = 0; ks < 4; ks++) qf[s][ks] = *(const bf16x8*)(qr + ks * 32);
  }

  // per-lane swizzled staging offsets (source chunk permuted; LDS stays linear for gl2lds)
  // K: instr i covers rows wid*16+i*4 .. +3 (4 rows x 16 chunks of 16B); pos p=lane&15 holds
  //    source chunk p ^ (row&15).  V: instr i covers rows wid*32+i*8 .. +7 (8 rows x 8 chunks);
  //    pos p=lane&7 holds source chunk p ^ (row&7).
  int koff[4], voff[4];
#pragma unroll
  for (int i = 0; i < 4; i++) {
    int krow = wid * 16 + i * 4 + (lane >> 4);
    int kch = (lane & 15) ^ ((i * 4 + (lane >> 4)) & 15);
    koff[i] = krow * 128 + kch * 8;
    int vrow = wid * 32 + i * 8 + (lane >> 3);
    int vch = (lane & 7) ^ (lane >> 3);
    voff[i] = vrow * 0 + vch * 8;  // vrow kept separately (long stride)
    voff[i] |= vrow << 16;         // pack: low 16 = col offset, high = row
  }

  auto stage = [&](int kt, int buf) {
    u16* kd = smem + buf * 8192;
    u16* vd = smem + 16384 + buf * 8192;
    const u16* ksrc = Kp + (long)kt * 64 * 128;
#pragma unroll
    for (int i = 0; i < 4; i++) {
      gl2lds16(ksrc + koff[i], kd + (wid * 16 + i * 4) * 128);
      int vrow = voff[i] >> 16, vcol = voff[i] & 0xffff;
      gl2lds16(Vp + (long)vrow * Sn + kt * 64 + vcol, vd + (wid * 32 + i * 8) * 64);
    }
  };

  f32x4 o[2][8];
#pragma unroll
  for (int s = 0; s < 2; s++)
#pragma unroll
    for (int i = 0; i < 8; i++) o[s][i] = f32x4{0.f, 0.f, 0.f, 0.f};
  float lsum[2][4] = {{0.f, 0.f, 0.f, 0.f}, {0.f, 0.f, 0.f, 0.f}};

  stage(kt0, 0);
  __syncthreads();  // compiler-inserted vmcnt(0) drains the DMA before the barrier

  for (int j = 0; j < tc; j++) {
    const int kt = kt0 + j;
    const int A = j & 1;
    if (j + 1 < tc) stage(kt + 1, A ^ 1);  // overlaps this iteration's compute
    const u16* sKc = smem + A * 8192;
    const u16* sVc = smem + 16384 + A * 8192;
    u16* sP = smem + 32768;
    const bool do0 = (kt <= 2 * qt2);  // strip0 inactive on strip1's diagonal tile

    // S = Q K^T  (K fragments read once, feed both strips)
    f32x4 sv0[4], sv1[4];
#pragma unroll
    for (int nt = 0; nt < 4; nt++) { sv0[nt] = f32x4{0.f, 0.f, 0.f, 0.f}; sv1[nt] = f32x4{0.f, 0.f, 0.f, 0.f}; }
#pragma unroll
    for (int ks = 0; ks < 4; ks++)
#pragma unroll
      for (int nt = 0; nt < 4; nt++) {
        bf16x8 bk = *(const bf16x8*)&sKc[(nt * 16 + l15) * 128 + (((ks * 4 + quad) ^ l15) & 15) * 8];
        if (do0) sv0[nt] = __builtin_amdgcn_mfma_f32_16x16x32_bf16(qf[0][ks], bk, sv0[nt], 0, 0, 0);
        sv1[nt] = __builtin_amdgcn_mfma_f32_16x16x32_bf16(qf[1][ks], bk, sv1[nt], 0, 0, 0);
      }
    // causal mask on diagonal tiles
    if (kt == 2 * qt2) {
#pragma unroll
      for (int nt = 0; nt < 4; nt++)
#pragma unroll
        for (int r = 0; r < 4; r++) {
          int rr = q0 + wid * 16 + quad * 4 + r, cc = kt * 64 + nt * 16 + l15;
          if (cc > rr) sv0[nt][r] = -1e30f;
        }
    }
    if (kt == jmaxall) {
#pragma unroll
      for (int nt = 0; nt < 4; nt++)
#pragma unroll
        for (int r = 0; r < 4; r++) {
          int rr = q0 + 64 + wid * 16 + quad * 4 + r, cc = kt * 64 + nt * 16 + l15;
          if (cc > rr) sv1[nt][r] = -1e30f;
        }
    }
    // per strip: exp -> sP (wave-private rows) -> PV
#pragma unroll
    for (int s = 0; s < 2; s++) {
      if (s == 0 && !do0) continue;
      const f32x4* sv = (s == 0) ? sv0 : sv1;
#pragma unroll
      for (int nt = 0; nt < 4; nt++)
#pragma unroll
        for (int r = 0; r < 4; r++) {
          float pe = __expf(sv[nt][r]);
          lsum[s][r] += pe;
          sP[(wid * 16 + quad * 4 + r) * 72 + nt * 16 + l15] = f2bf(pe);
        }
#pragma unroll
      for (int ks = 0; ks < 2; ks++) {
        bf16x8 pa = *(const bf16x8*)&sP[(wid * 16 + l15) * 72 + ks * 32 + quad * 8];
#pragma unroll
        for (int dt = 0; dt < 8; dt++) {
          bf16x8 vv = *(const bf16x8*)&sVc[(dt * 16 + l15) * 64 + (((ks * 4 + quad) ^ (l15 & 7)) & 7) * 8];
          o[s][dt] = __builtin_amdgcn_mfma_f32_16x16x32_bf16(pa, vv, o[s][dt], 0, 0, 0);
        }
      }
    }
    __syncthreads();  // drains next tile's DMA; publishes before buffer swap
  }

  // ---- epilogue: reduce row sums, repack via LDS (smem dead), coalesced uint4 stores ----
  float rs[2][4];
#pragma unroll
  for (int s = 0; s < 2; s++)
#pragma unroll
    for (int r = 0; r < 4; r++) {
      float t = lsum[s][r];
      t += __shfl_xor(t, 1); t += __shfl_xor(t, 2); t += __shfl_xor(t, 4); t += __shfl_xor(t, 8);
      rs[s][r] = t;
    }
  u16* sT = smem;  // [64][132] staging (8448 u16)
#pragma unroll
  for (int s = 0; s < 2; s++) {
    float iv[4];
#pragma unroll
    for (int r = 0; r < 4; r++) iv[r] = split ? 1.f : 1.f / rs[s][r];
#pragma unroll
    for (int dt = 0; dt < 8; dt++)
#pragma unroll
      for (int r = 0; r < 4; r++)
        sT[(wid * 16 + quad * 4 + r) * 132 + dt * 16 + l15] = f2bf(o[s][dt][r] * iv[r]);
    __syncthreads();
    if (!split) {
#pragma unroll
      for (int rep = 0; rep < 4; rep++) {
        int row = rep * 16 + (tid >> 4);
        int c8 = (tid & 15) * 8;
        uint4 v = *(const uint4*)&sT[row * 132 + c8];
        *(uint4*)(attn + ((long)(b * Sn + q0 + s * 64 + row)) * (long)Hdim + h * Dh + c8) = v;
      }
    } else {
      u16* op = (ch == 0 ? o0 : o1) + ((long)bh * Sn + q0 + s * 64) * Dh;
#pragma unroll
      for (int rep = 0; rep < 4; rep++) {
        int row = rep * 16 + (tid >> 4);
        int c8 = (tid & 15) * 8;
        uint4 v = *(const uint4*)&sT[row * 132 + c8];
        *(uint4*)(op + (long)row * Dh + c8) = v;
      }
    }
    __syncthreads();
  }
  if (split && l15 == 0) {
    float* lp = (ch == 0 ? ls0 : ls1) + (long)bh * Sn + q0;
#pragma unroll
    for (int s = 0; s < 2; s++)
#pragma unroll
      for (int r = 0; r < 4; r++) lp[s * 64 + wid * 16 + quad * 4 + r] = rs[s][r];
  }
}

// combine bf16 chunk partials for rows 1024..2047, normalize, emit attn bf16 (coalesced)
__global__ void attn_norm6_k(const u16* __restrict__ o0, const u16* __restrict__ o1,
                             const float* __restrict__ l0, const float* __restrict__ l1,
                             u16* __restrict__ attn) {
  const int gid = blockIdx.x;  // 24 bh * 64 row-groups of 16
  const int bh = gid >> 6, rb = gid & 63;
  const int row = 1024 + rb * 16 + (threadIdx.x >> 4);
  const int ch = (threadIdx.x & 15) * 8;
  const long idx = ((long)bh * Sn + row) * Dh + ch;
  union { uint4 v; u16 s[8]; } a, b2, ov;
  a.v = *(const uint4*)(o0 + idx);
  b2.v = *(const uint4*)(o1 + idx);
  const float inv = 1.f / (l0[(long)bh * Sn + row] + l1[(long)bh * Sn + row]);
#pragma unroll
  for (int k = 0; k < 8; k++) ov.s[k] = f2bf((bf2f(a.s[k]) + bf2f(b2.s[k])) * inv);
  const int b = bh / 12, h = bh % 12;
  *(uint4*)(attn + ((long)(b * Sn + row)) * (long)Hdim + h * Dh + ch) = ov.v;
}

// ---------------- host ----------------

extern "C" void kernel_launch(void* const* d_in, const int* in_sizes, int n_in,
                              void* d_out, int out_size, void* d_ws, size_t ws_size,
                              hipStream_t stream) {
  const float* hidden = (const float*)d_in[0];
  const int* pos = (const int*)d_in[1];
  const float* cosT = (const float*)d_in[2];
  const float* sinT = (const float*)d_in[3];
  const float* ln1 = (const float*)d_in[4];
  const float* ln2 = (const float*)d_in[5];
  const float* wq = (const float*)d_in[6];
  const float* wk = (const float*)d_in[7];
  const float* wv = (const float*)d_in[8];
  const float* wo = (const float*)d_in[9];
  const float* router_w = (const float*)d_in[10];
  const float* w_gate = (const float*)d_in[11];
  const float* w_up = (const float*)d_in[12];
  const float* w_down = (const float*)d_in[13];
  const float* shared_in = (const float*)d_in[14];
  const float* shared_out = (const float*)d_in[15];
  float* out = (float*)d_out;

  // ---- workspace layout with phase-based aliasing ----
  char* p = (char*)d_ws;
  auto alloc = [&](size_t bytes) -> char* {
    char* r = p; p += (bytes + 255) & ~(size_t)255; return r;
  };
  u16* wqkv_b = (u16*)alloc((size_t)2560 * Hdim * 2);
  u16* wo_b = (u16*)alloc((size_t)Hdim * Hdim * 2);
  u16* wgu_b = (u16*)alloc((size_t)NE * 1024 * Hdim * 2);
  u16* wdown_b = (u16*)alloc((size_t)NE * Hdim * IEXP * 2);
  u16* wshin_b = (u16*)alloc((size_t)2048 * Hdim * 2);
  u16* wshout_b = (u16*)alloc((size_t)Hdim * ISH * 2);
  char* regH = alloc((size_t)Tn * Hdim * 4);                // x1n | attn-partial slot0 | hidden2
  char* reg1 = alloc((size_t)Tn * 2560 * 2);                // qkvraw | attn | gu | shraw
  char* reg2 = alloc((size_t)Bn * NHq * Sn * Dh * 2);       // qbuf | x2n | shy
  char* reg3 = alloc((size_t)2 * Bn * NKVh * Sn * Dh * 2);  // kbuf+vT | act | shact
  u16* Y_b = (u16*)alloc((size_t)2 * Tn * Hdim * 2);        // also attn-partial slot1
  int* tidx = (int*)alloc(Tn * 2 * 4);
  float* tw = (float*)alloc(Tn * 2 * 4);
  int* tokslot = (int*)alloc(Tn * 2 * 4);
  int* perm = (int*)alloc(Tn * 2 * 4);
  float* slotw = (float*)alloc(Tn * 2 * 4);
  int* counts = (int*)alloc(64);
  int* seg = (int*)alloc(64);
  int* cursor = (int*)alloc(64);
  float* lsum0 = (float*)alloc((size_t)24 * Sn * 4);
  float* lsum1 = (float*)alloc((size_t)24 * Sn * 4);

  u16* x1n = (u16*)regH;
  float* hidden2 = (float*)regH;
  u16* opart0 = (u16*)regH;  // bf16 partials, rows>=1024 only; region free during attention
  u16* opart1 = (u16*)Y_b;   // Y written later
  u16* qkvraw = (u16*)reg1;
  u16* attn = (u16*)reg1;
  u16* gu_b = (u16*)reg1;
  u16* shraw_b = (u16*)reg1;
  u16* qbuf = (u16*)reg2;
  u16* x2n = (u16*)reg2;
  u16* shy_b = (u16*)reg2;
  u16* kbuf = (u16*)reg3;
  u16* vtbuf = kbuf + (size_t)Bn * NKVh * Sn * Dh;  // transposed V [b][hk][d][s]
  u16* act_b = (u16*)reg3;
  u16* shact_b = (u16*)reg3;

  auto cdiv = [](long a, long b) { return (int)((a + b - 1) / b); };

  // fused weight conversion (+ counts zeroing)
  cvt_all_k<<<(int)(B7 / 256), 256, 0, stream>>>(
      (const float4*)wq, (const float4*)wk, (const float4*)wv, (const float4*)wo,
      (const float4*)w_gate, (const float4*)w_up, (const float4*)w_down,
      (const float4*)shared_in, (const float4*)shared_out,
      (ushort4*)wqkv_b, (ushort4*)wo_b, (ushort4*)wgu_b, (ushort4*)wdown_b,
      (ushort4*)wshin_b, (ushort4*)wshout_b, counts);

  // attention block
  rmsnorm_k<<<Tn, 256, 0, stream>>>(hidden, ln1, x1n);
  gemm_bt<0><<<dim3(2560 / 128, Tn / 128, 1), 256, 0, stream>>>(
      x1n, wqkv_b, nullptr, qkvraw, nullptr, nullptr, nullptr, nullptr, Tn, 2560, Hdim, 0);
  rope_k<<<Tn, 256, 0, stream>>>(qkvraw, pos, cosT, sinT, qbuf, kbuf);
  vt_k<<<dim3(Sn / 64, Dh / 64, Bn * NKVh), 256, 0, stream>>>(qkvraw, vtbuf);
  flash7_k<<<dim3(576, 1, 1), 256, 0, stream>>>(qbuf, kbuf, vtbuf, opart0, opart1, lsum0, lsum1, attn);
  attn_norm6_k<<<dim3(24 * 64, 1, 1), 256, 0, stream>>>(opart0, opart1, lsum0, lsum1, attn);
  gemm_bt<2><<<dim3(Hdim / 128, Tn / 128, 1), 256, 0, stream>>>(
      attn, wo_b, hidden2, nullptr, hidden, nullptr, nullptr, nullptr, Tn, Hdim, Hdim, 0);

  // MoE block
  rmsnorm_k<<<Tn, 256, 0, stream>>>(hidden2, ln2, x2n);
  router_k<<<Tn / 4, 256, 0, stream>>>(hidden2, ln2, router_w, tidx, tw, counts);
  scan_k<<<1, 64, 0, stream>>>(counts, seg, cursor);
  scatter_k<<<cdiv(Tn, 256), 256, 0, stream>>>(tidx, tw, cursor, perm, slotw, tokslot);
  gemm_bt<0><<<dim3(1024 / 128, Tn / 128, NE), 256, 0, stream>>>(
      x2n, wgu_b, nullptr, gu_b, nullptr, perm, counts, seg, 0, 1024, Hdim, (long)1024 * Hdim);
  act_moe_k<<<cdiv((long)2 * Tn * IEXP / 8, 256), 256, 0, stream>>>(gu_b, slotw, act_b);
  gemm_bt<0><<<dim3(Hdim / 128, Tn / 128, NE), 256, 0, stream>>>(
      act_b, wdown_b, nullptr, Y_b, nullptr, nullptr, counts, seg, 0, Hdim, IEXP, (long)Hdim * IEXP);

  // shared MLP
  gemm_bt<0><<<dim3(2048 / 128, Tn / 128, 1), 256, 0, stream>>>(
      x2n, wshin_b, nullptr, shraw_b, nullptr, nullptr, nullptr, nullptr, Tn, 2048, Hdim, 0);
  act_sh_k<<<cdiv((long)Tn * ISH / 8, 256), 256, 0, stream>>>(shraw_b, shact_b);
  gemm_bt<0><<<dim3(Hdim / 128, Tn / 128, 1), 256, 0, stream>>>(
      shact_b, wshout_b, nullptr, shy_b, nullptr, nullptr, nullptr, nullptr, Tn, Hdim, ISH, 0);

  // combine
  final_k<<<cdiv((long)Tn * Hdim / 4, 256), 256, 0, stream>>>(hidden2, shy_b, Y_b, tokslot, out);
}

// Round 5
// 590.257 us; speedup vs baseline: 1.3323x; 1.1790x over previous
//
#include <hip/hip_runtime.h>
#include <cstdint>
#include <cstddef>

using u16 = unsigned short;
using u32 = unsigned int;

typedef __bf16 bf16x8 __attribute__((ext_vector_type(8)));
typedef float  f32x4  __attribute__((ext_vector_type(4)));

#define DI __device__ __forceinline__

constexpr int Hdim = 1536;
constexpr int NHq = 12, NKVh = 4, Dh = 128;
constexpr int NE = 8, IEXP = 512, ISH = 1024;
constexpr int Bn = 2, Sn = 2048, Tn = Bn * Sn;
constexpr float RESM = 0.22f;

DI float bf2f(u16 u) { union { u32 i; float f; } c; c.i = (u32)u << 16; return c.f; }
DI u16 f2bf(float f) {
  union { float f; u32 i; } c; c.f = f;
  u32 r = c.i + 0x7fffu + ((c.i >> 16) & 1u);
  return (u16)(r >> 16);
}

DI void gl2lds16(const u16* g, u16* l) {
  __builtin_amdgcn_global_load_lds((__attribute__((address_space(1))) void*)g,
                                   (__attribute__((address_space(3))) void*)l, 16, 0, 0);
}

// flash7 LPT rank tables: (qt2, chunk) sorted by descending tile count.
// qt2<=7: single chunk (tiles 0..2qt2+1). qt2>=8: chunkA tiles 0..15, chunkB tiles 16..2qt2+1.
__constant__ signed char c_qt2[24] = {7,8,9,10,11,12,13,14,15,15,6,14,5,13,4,12,3,11,2,10,1,9,0,8};
__constant__ signed char c_ch[24]  = {0,0,0,0,0,0,0,0,0,1, 0,1, 0,1, 0,1, 0,1, 0,1, 0,1, 0,1};

// ---------------- fused weight conversion (all weights, one launch) ----------------
constexpr long B0 = 589824;        // wq  -> wqkv[0..)
constexpr long B1 = B0 + 196608;   // wk
constexpr long B2 = B1 + 196608;   // wv
constexpr long B3 = B2 + 589824;   // wo
constexpr long B4 = B3 + 3145728;  // wgu interleaved
constexpr long B5 = B4 + 1572864;  // wdown
constexpr long B6 = B5 + 786432;   // wshin
constexpr long B7 = B6 + 393216;   // wshout ; total 7471104 f4 = 29184 blocks

__global__ void cvt_all_k(const float4* __restrict__ wq, const float4* __restrict__ wk,
                          const float4* __restrict__ wv, const float4* __restrict__ wo,
                          const float4* __restrict__ wg, const float4* __restrict__ wu,
                          const float4* __restrict__ wd, const float4* __restrict__ wsi,
                          const float4* __restrict__ wso,
                          ushort4* __restrict__ qkvb, ushort4* __restrict__ wob,
                          ushort4* __restrict__ wgub, ushort4* __restrict__ wdnb,
                          ushort4* __restrict__ wsib, ushort4* __restrict__ wsob) {
  long i = (long)blockIdx.x * 256 + threadIdx.x;
  float4 v; ushort4* dst;
  if (i < B0) { v = wq[i]; dst = qkvb + i; }
  else if (i < B1) { v = wk[i - B0]; dst = qkvb + i; }
  else if (i < B2) { v = wv[i - B1]; dst = qkvb + i; }
  else if (i < B3) { v = wo[i - B2]; dst = wob + (i - B2); }
  else if (i < B4) {
    long k = i - B3;
    long e = k / 393216, rem = k % 393216;
    long r = rem / 384, h4 = rem % 384;
    v = (r < 512) ? wg[(e * 512 + r) * 384 + h4] : wu[(e * 512 + (r - 512)) * 384 + h4];
    dst = wgub + k;
  }
  else if (i < B5) { v = wd[i - B4]; dst = wdnb + (i - B4); }
  else if (i < B6) { v = wsi[i - B5]; dst = wsib + (i - B5); }
  else { v = wso[i - B6]; dst = wsob + (i - B6); }
  *dst = ushort4{f2bf(v.x), f2bf(v.y), f2bf(v.z), f2bf(v.w)};
}

// ---------------- elementwise / small kernels ----------------

__global__ void rmsnorm_k(const float* __restrict__ x, const float* __restrict__ w, u16* __restrict__ o) {
  __shared__ float red[4];
  long t = blockIdx.x;
  const float* row = x + t * Hdim;
  float ss = 0.f;
  for (int i = threadIdx.x; i < Hdim; i += 256) { float v = row[i]; ss += v * v; }
#pragma unroll
  for (int m = 32; m >= 1; m >>= 1) ss += __shfl_xor(ss, m);
  if ((threadIdx.x & 63) == 0) red[threadIdx.x >> 6] = ss;
  __syncthreads();
  float tot = red[0] + red[1] + red[2] + red[3];
  float sc = rsqrtf(tot * (1.f / Hdim) + 1e-6f);
  for (int i = threadIdx.x; i < Hdim; i += 256) o[t * Hdim + i] = f2bf(row[i] * sc * w[i]);
}

// qkv_raw [T,2560] -> q [B,NH,S,D]*SCALE , k [B,NKV,S,D]   (V handled by vt_k)
__global__ void rope_k(const u16* __restrict__ qkv, const int* __restrict__ pos,
                       const float* __restrict__ cosT, const float* __restrict__ sinT,
                       u16* __restrict__ qb, u16* __restrict__ kb) {
  int t = blockIdx.x;
  int b = t >> 11, s = t & 2047;
  int p = pos[t];
  const u16* row = qkv + (long)t * 2560;
  const float* cp = cosT + (long)p * Dh;
  const float* sp = sinT + (long)p * Dh;
  for (int idx = threadIdx.x; idx < NHq * Dh; idx += 256) {
    int hh = idx >> 7, d = idx & 127;
    float x = bf2f(row[idx]);
    float xr = (d < 64) ? -bf2f(row[hh * 128 + d + 64]) : bf2f(row[hh * 128 + d - 64]);
    float v = x * cp[d] + xr * sp[d];
    qb[((long)(b * NHq + hh) * Sn + s) * Dh + d] = f2bf(v * 0.0078125f); // fold SCALE=2^-7
  }
  for (int idx = threadIdx.x; idx < NKVh * Dh; idx += 256) {
    int hh = idx >> 7, d = idx & 127;
    float x = bf2f(row[1536 + idx]);
    float xr = (d < 64) ? -bf2f(row[1536 + hh * 128 + d + 64]) : bf2f(row[1536 + hh * 128 + d - 64]);
    float v = x * cp[d] + xr * sp[d];
    kb[((long)(b * NKVh + hh) * Sn + s) * Dh + d] = f2bf(v);
  }
}

// transpose V out of qkvraw: vT[b][hk][d][s] = qkvraw[b*Sn+s][2048 + hk*128 + d]
__global__ void vt_k(const u16* __restrict__ qkv, u16* __restrict__ vt) {
  __shared__ __align__(16) u16 tile[64][72];
  const int s0 = blockIdx.x * 64, d0 = blockIdx.y * 64, bh = blockIdx.z;
  const int b = bh >> 2, hk = bh & 3;
  const int tid = threadIdx.x;
#pragma unroll
  for (int ph = 0; ph < 2; ph++) {
    int e = ph * 256 + tid;
    int r = e >> 3, c = e & 7;
    uint4 v = *(const uint4*)(qkv + (long)(b * Sn + s0 + r) * 2560 + 2048 + hk * 128 + d0 + c * 8);
    *(uint4*)&tile[r][c * 8] = v;
  }
  __syncthreads();
#pragma unroll
  for (int ph = 0; ph < 2; ph++) {
    int e = ph * 256 + tid;
    int rr = e >> 3, cc = e & 7;
    union { uint4 v; u16 s[8]; } tmp;
#pragma unroll
    for (int i = 0; i < 8; i++) tmp.s[i] = tile[cc * 8 + i][rr];
    *(uint4*)(vt + ((long)(bh * Dh) + d0 + rr) * Sn + s0 + cc * 8) = tmp.v;
  }
}

// fp32 router: recompute rmsnorm from hidden2 (fp32) to match reference logits exactly.
// NO atomics: 8192 same-line device atomics measured ~105us (serialized at coherence point).
__global__ void router_k(const float* __restrict__ hid2, const float* __restrict__ ln2,
                         const float* __restrict__ rw,
                         int* __restrict__ tidx, float* __restrict__ tw) {
  int wid = threadIdx.x >> 6, lane = threadIdx.x & 63;
  long t = (long)blockIdx.x * 4 + wid;
  const float* x = hid2 + t * Hdim;
  float xv[24];
  float ss = 0.f;
#pragma unroll
  for (int i = 0; i < 24; i++) { float v = x[lane + i * 64]; xv[i] = v; ss += v * v; }
#pragma unroll
  for (int m = 32; m >= 1; m >>= 1) ss += __shfl_xor(ss, m);
  float sc = rsqrtf(ss * (1.f / Hdim) + 1e-6f);
#pragma unroll
  for (int i = 0; i < 24; i++) xv[i] = xv[i] * sc * ln2[lane + i * 64];
  float lg[8];
  for (int e = 0; e < 8; e++) {
    const float* wrow = rw + e * Hdim;
    float s = 0.f;
#pragma unroll
    for (int i = 0; i < 24; i++) s += xv[i] * wrow[lane + i * 64];
#pragma unroll
    for (int m = 32; m >= 1; m >>= 1) s += __shfl_xor(s, m);
    lg[e] = s;
  }
  if (lane == 0) {
    int i0 = 0; float b0 = lg[0];
    for (int e = 1; e < 8; e++) if (lg[e] > b0) { b0 = lg[e]; i0 = e; }
    int i1 = -1; float b1 = -3e38f;
    for (int e = 0; e < 8; e++) if (e != i0 && lg[e] > b1) { b1 = lg[e]; i1 = e; }
    float w1 = 1.f / (1.f + __expf(b0 - b1));
    float w0 = 1.f - w1;
    tidx[2 * t] = i0; tidx[2 * t + 1] = i1;
    tw[2 * t] = w0; tw[2 * t + 1] = w1;
  }
}

// single-workgroup deterministic routing scan: histogram + 2-level exclusive prefix + slot
// assignment. Replaces scan_k + atomic scatter_k (scatter's 8192 same-line atomics = twin of
// router's 105us pathology). Register histogram (unrolled, no scratch), LDS prefix, ~8us.
__global__ void route_scan_k(const int* __restrict__ tidx, const float* __restrict__ tw,
                             int* __restrict__ perm, float* __restrict__ slotw,
                             int* __restrict__ tokslot, int* __restrict__ counts,
                             int* __restrict__ seg) {
  __shared__ int pref[8][257];  // pref[e][t+1] = inclusive per-thread counts; pref[e][0]=0
  __shared__ int segs[8];
  const int tid = threadIdx.x;
  const int base = tid * 32;  // 256 threads x 32 entries = 8192
  int le[32];
#pragma unroll
  for (int j = 0; j < 32; j++) le[j] = tidx[base + j];
#pragma unroll
  for (int e = 0; e < 8; e++) {
    int c = 0;
#pragma unroll
    for (int j = 0; j < 32; j++) c += (le[j] == e) ? 1 : 0;
    pref[e][tid + 1] = c;
  }
  if (tid < 8) pref[tid][0] = 0;
  __syncthreads();
  if (tid < 8) {  // serial scan per expert (8 threads in parallel, 256 iters each)
    int acc = 0;
    for (int t2 = 0; t2 < 256; t2++) { acc += pref[tid][t2 + 1]; pref[tid][t2 + 1] = acc; }
    counts[tid] = acc;
  }
  __syncthreads();
  if (tid == 0) {
    int acc = 0;
    for (int e = 0; e < 8; e++) { segs[e] = acc; seg[e] = acc; acc += pref[e][256]; }
  }
  __syncthreads();
#pragma unroll
  for (int j = 0; j < 32; j++) {
    int e = le[j];
    int rank = 0;
#pragma unroll
    for (int j2 = 0; j2 < 32; j2++)
      if (j2 < j) rank += (le[j2] == e) ? 1 : 0;
    int p = segs[e] + pref[e][tid] + rank;
    perm[p] = (base + j) >> 1;
    slotw[p] = tw[base + j];
    tokslot[base + j] = p;
  }
}

__global__ void act_moe_k(const u16* __restrict__ gu, const float* __restrict__ slotw,
                          u16* __restrict__ act) {
  long i8 = (long)blockIdx.x * 256 + threadIdx.x;  // 8 elems per thread
  if (i8 >= (long)2 * Tn * IEXP / 8) return;
  long slot = i8 / 64; int c8 = (int)(i8 % 64);
  union { uint4 v; u16 s[8]; } gv, uv, ov;
  gv.v = *(const uint4*)(gu + slot * 1024 + c8 * 8);
  uv.v = *(const uint4*)(gu + slot * 1024 + 512 + c8 * 8);
  float sw = slotw[slot];
#pragma unroll
  for (int k = 0; k < 8; k++) {
    float g = bf2f(gv.s[k]), u = bf2f(uv.s[k]);
    ov.s[k] = f2bf((g / (1.f + __expf(-g))) * u * sw);
  }
  *(uint4*)(act + i8 * 8) = ov.v;
}

__global__ void act_sh_k(const u16* __restrict__ shr, u16* __restrict__ act) {
  long i8 = (long)blockIdx.x * 256 + threadIdx.x;
  if (i8 >= (long)Tn * ISH / 8) return;
  long t = i8 / 128; int c8 = (int)(i8 % 128);
  union { uint4 v; u16 s[8]; } av, bv, ov;
  av.v = *(const uint4*)(shr + t * 2048 + c8 * 8);
  bv.v = *(const uint4*)(shr + t * 2048 + 1024 + c8 * 8);
#pragma unroll
  for (int k = 0; k < 8; k++) {
    float a = bf2f(av.s[k]), b = bf2f(bv.s[k]);
    ov.s[k] = f2bf((a / (1.f + __expf(-a))) * b);
  }
  *(uint4*)(act + i8 * 8) = ov.v;
}

__global__ void final_k(const float* __restrict__ hidden2, const u16* __restrict__ shy,
                        const u16* __restrict__ Y, const int* __restrict__ tokslot,
                        float* __restrict__ out) {
  long i4 = (long)blockIdx.x * 256 + threadIdx.x;  // 4 elems per thread
  if (i4 >= (long)Tn * Hdim / 4) return;
  long t = i4 / 384; int h4 = (int)(i4 % 384);
  long s0 = tokslot[2 * t], s1 = tokslot[2 * t + 1];
  float4 hv = *(const float4*)(hidden2 + i4 * 4);
  ushort4 sv = *(const ushort4*)(shy + i4 * 4);
  ushort4 y0 = *(const ushort4*)(Y + s0 * Hdim + h4 * 4);
  ushort4 y1 = *(const ushort4*)(Y + s1 * Hdim + h4 * 4);
  float4 r;
  r.x = hv.x + (bf2f(sv.x) + bf2f(y0.x) + bf2f(y1.x)) * RESM;
  r.y = hv.y + (bf2f(sv.y) + bf2f(y0.y) + bf2f(y1.y)) * RESM;
  r.z = hv.z + (bf2f(sv.z) + bf2f(y0.z) + bf2f(y1.z)) * RESM;
  r.w = hv.w + (bf2f(sv.w) + bf2f(y0.w) + bf2f(y1.w)) * RESM;
  *(float4*)(out + i4 * 4) = r;
}

// ---------------- GEMM: C[M,N] = A[M,K] @ B[N,K]^T (bf16 in, fp32 acc) ----------------
template <int EPI>
__global__ __launch_bounds__(256) void gemm_bt(
    const u16* __restrict__ A, const u16* __restrict__ Bb,
    float* __restrict__ Cf, u16* __restrict__ Cb, const float* __restrict__ res,
    const int* __restrict__ perm, const int* __restrict__ counts, const int* __restrict__ segoff,
    int M, int N, int K, long bstride) {
  __shared__ __align__(16) u16 smem[8448];   // As[4096] | Bs[4096]; epilogue stage [64][132]
  u16* As = smem;
  u16* Bs = smem + 4096;
  const int e = blockIdx.z;
  const u16* Bp = Bb + (long)e * bstride;
  const int meff = counts ? counts[e] : M;
  const int base = segoff ? segoff[e] : 0;
  const int m0 = blockIdx.y * 128;
  if (m0 >= meff) return;
  const int n0 = blockIdx.x * 128;
  const int tid = threadIdx.x;
  const int lane = tid & 63, wid = tid >> 6;
  const int l15 = lane & 15, quad = lane >> 4;
  const int wm = wid & 1, wn = wid >> 1;

  const int r0 = tid >> 2, c0 = (tid & 3) * 8;
  int g0 = m0 + r0; if (g0 >= meff) g0 = meff - 1;
  int g1 = m0 + r0 + 64; if (g1 >= meff) g1 = meff - 1;
  const long arow0 = perm ? (long)perm[base + g0] : (long)(base + g0);
  const long arow1 = perm ? (long)perm[base + g1] : (long)(base + g1);
  const long brow0 = n0 + r0, brow1 = n0 + r0 + 64;

  f32x4 acc[4][4];
#pragma unroll
  for (int i = 0; i < 4; i++)
#pragma unroll
    for (int j = 0; j < 4; j++) acc[i][j] = f32x4{0.f, 0.f, 0.f, 0.f};

  for (int k0 = 0; k0 < K; k0 += 32) {
    __syncthreads();
    gl2lds16(A + arow0 * K + k0 + c0, &As[tid * 8]);
    gl2lds16(A + arow1 * K + k0 + c0, &As[(tid + 256) * 8]);
    gl2lds16(Bp + brow0 * K + k0 + c0, &Bs[tid * 8]);
    gl2lds16(Bp + brow1 * K + k0 + c0, &Bs[(tid + 256) * 8]);
    __syncthreads();
    bf16x8 af[4], bfr[4];
#pragma unroll
    for (int i = 0; i < 4; i++) af[i] = *(const bf16x8*)&As[(wm * 64 + i * 16 + l15) * 32 + quad * 8];
#pragma unroll
    for (int j = 0; j < 4; j++) bfr[j] = *(const bf16x8*)&Bs[(wn * 64 + j * 16 + l15) * 32 + quad * 8];
#pragma unroll
    for (int i = 0; i < 4; i++)
#pragma unroll
      for (int j = 0; j < 4; j++)
        acc[i][j] = __builtin_amdgcn_mfma_f32_16x16x32_bf16(af[i], bfr[j], acc[i][j], 0, 0, 0);
  }

  __syncthreads();  // As/Bs dead; reuse as epilogue staging
  if (EPI == 0) {
    // bf16 out: two halves (rows wm*64..), stage [64][132], coalesced uint4 stores
    u16* sT = smem;
#pragma unroll
    for (int half = 0; half < 2; half++) {
      if (wm == half) {
#pragma unroll
        for (int i = 0; i < 4; i++)
#pragma unroll
          for (int j = 0; j < 4; j++)
#pragma unroll
            for (int r = 0; r < 4; r++)
              sT[(i * 16 + quad * 4 + r) * 132 + wn * 64 + j * 16 + l15] = f2bf(acc[i][j][r]);
      }
      __syncthreads();
#pragma unroll
      for (int rep = 0; rep < 4; rep++) {
        int lr = rep * 16 + (tid >> 4);
        int gm = m0 + half * 64 + lr;
        if (gm < meff) {
          int ch = (tid & 15) * 8;
          uint4 v = *(const uint4*)&sT[lr * 132 + ch];
          *(uint4*)(Cb + (long)(base + gm) * N + n0 + ch) = v;
        }
      }
      __syncthreads();
    }
  } else {
    // fp32 out with residual: four phases of 32 rows, stage f32 [32][132]
    float* sF = (float*)smem;
#pragma unroll
    for (int ph = 0; ph < 4; ph++) {
      if (wm == (ph >> 1)) {
#pragma unroll
        for (int ii = 0; ii < 2; ii++) {
          int i = (ph & 1) * 2 + ii;
#pragma unroll
          for (int j = 0; j < 4; j++)
#pragma unroll
            for (int r = 0; r < 4; r++)
              sF[(ii * 16 + quad * 4 + r) * 132 + wn * 64 + j * 16 + l15] = acc[i][j][r];
        }
      }
      __syncthreads();
#pragma unroll
      for (int rep = 0; rep < 2; rep++) {
        int lr = rep * 16 + (tid >> 4);
        int gm = m0 + ph * 32 + lr;
        if (gm < meff) {
          int ch = (tid & 15) * 8;  // 8 floats
          long idx = (long)(base + gm) * N + n0 + ch;
          float4 a0 = *(const float4*)&sF[lr * 132 + ch];
          float4 a1 = *(const float4*)&sF[lr * 132 + ch + 4];
          float4 r0v = *(const float4*)&res[idx];
          float4 r1v = *(const float4*)&res[idx + 4];
          float4 o0v{r0v.x + a0.x * RESM, r0v.y + a0.y * RESM, r0v.z + a0.z * RESM, r0v.w + a0.w * RESM};
          float4 o1v{r1v.x + a1.x * RESM, r1v.y + a1.y * RESM, r1v.z + a1.z * RESM, r1v.w + a1.w * RESM};
          *(float4*)&Cf[idx] = o0v;
          *(float4*)&Cf[idx + 4] = o1v;
        }
      }
      __syncthreads();
    }
  }
}

// ---------------- flash attention v7: BQ=128, gl2lds double-buffer, swizzled linear LDS ----------
__global__ __launch_bounds__(256, 2) void flash7_k(
    const u16* __restrict__ qb, const u16* __restrict__ kb, const u16* __restrict__ vt,
    u16* __restrict__ o0, u16* __restrict__ o1,
    float* __restrict__ ls0, float* __restrict__ ls1,
    u16* __restrict__ attn) {
  // sK[2][64*128] @0, sV[2][128*64] @16384, sP[64*72] @32768  (u16 units; 74752 B total)
  __shared__ __align__(16) u16 smem[37376];
  const int rnk = blockIdx.x / 24, bh = blockIdx.x % 24;
  const int qt2 = c_qt2[rnk], ch = c_ch[rnk];
  const int jmaxall = 2 * qt2 + 1;
  const int kt0 = ch ? 16 : 0;
  const int ktend = ch ? jmaxall : (jmaxall < 15 ? jmaxall : 15);
  const int tc = ktend - kt0 + 1;
  const bool split = (qt2 >= 8);
  const int b = bh / 12, h = bh % 12, hk = h / 3;
  const int q0 = qt2 * 128;
  const u16* Q = qb + (long)(b * NHq + h) * Sn * Dh;
  const u16* Kp = kb + (long)(b * NKVh + hk) * Sn * Dh;
  const u16* Vp = vt + (long)(b * NKVh + hk) * Dh * Sn;  // [d][s]
  const int tid = threadIdx.x, lane = tid & 63, wid = tid >> 6;
  const int l15 = lane & 15, quad = lane >> 4;

  // loop-invariant Q fragments for both strips (wave wid owns rows wid*16..+15 of each strip)
  bf16x8 qf[2][4];
#pragma unroll
  for (int s = 0; s < 2; s++) {
    const u16* qr = Q + (long)(q0 + s * 64 + wid * 16 + l15) * Dh + quad * 8;
#pragma unroll
    for (int ks = 0; ks < 4; ks++) qf[s][ks] = *(const bf16x8*)(qr + ks * 32);
  }

  // per-lane swizzled staging offsets (source chunk permuted; LDS stays linear for gl2lds)
  int koff[4], voff[4];
#pragma unroll
  for (int i = 0; i < 4; i++) {
    int krow = wid * 16 + i * 4 + (lane >> 4);
    int kch = (lane & 15) ^ ((i * 4 + (lane >> 4)) & 15);
    koff[i] = krow * 128 + kch * 8;
    int vrow = wid * 32 + i * 8 + (lane >> 3);
    int vch = (lane & 7) ^ (lane >> 3);
    voff[i] = vch * 8;
    voff[i] |= vrow << 16;  // pack: low 16 = col offset, high = row
  }

  auto stage = [&](int kt, int buf) {
    u16* kd = smem + buf * 8192;
    u16* vd = smem + 16384 + buf * 8192;
    const u16* ksrc = Kp + (long)kt * 64 * 128;
#pragma unroll
    for (int i = 0; i < 4; i++) {
      gl2lds16(ksrc + koff[i], kd + (wid * 16 + i * 4) * 128);
      int vrow = voff[i] >> 16, vcol = voff[i] & 0xffff;
      gl2lds16(Vp + (long)vrow * Sn + kt * 64 + vcol, vd + (wid * 32 + i * 8) * 64);
    }
  };

  f32x4 o[2][8];
#pragma unroll
  for (int s = 0; s < 2; s++)
#pragma unroll
    for (int i = 0; i < 8; i++) o[s][i] = f32x4{0.f, 0.f, 0.f, 0.f};
  float lsum[2][4] = {{0.f, 0.f, 0.f, 0.f}, {0.f, 0.f, 0.f, 0.f}};

  stage(kt0, 0);
  __syncthreads();  // compiler-inserted vmcnt(0) drains the DMA before the barrier

  for (int j = 0; j < tc; j++) {
    const int kt = kt0 + j;
    const int A = j & 1;
    if (j + 1 < tc) stage(kt + 1, A ^ 1);  // overlaps this iteration's compute
    const u16* sKc = smem + A * 8192;
    const u16* sVc = smem + 16384 + A * 8192;
    u16* sP = smem + 32768;
    const bool do0 = (kt <= 2 * qt2);  // strip0 inactive on strip1's diagonal tile

    // S = Q K^T  (K fragments read once, feed both strips)
    f32x4 sv0[4], sv1[4];
#pragma unroll
    for (int nt = 0; nt < 4; nt++) { sv0[nt] = f32x4{0.f, 0.f, 0.f, 0.f}; sv1[nt] = f32x4{0.f, 0.f, 0.f, 0.f}; }
#pragma unroll
    for (int ks = 0; ks < 4; ks++)
#pragma unroll
      for (int nt = 0; nt < 4; nt++) {
        bf16x8 bk = *(const bf16x8*)&sKc[(nt * 16 + l15) * 128 + (((ks * 4 + quad) ^ l15) & 15) * 8];
        if (do0) sv0[nt] = __builtin_amdgcn_mfma_f32_16x16x32_bf16(qf[0][ks], bk, sv0[nt], 0, 0, 0);
        sv1[nt] = __builtin_amdgcn_mfma_f32_16x16x32_bf16(qf[1][ks], bk, sv1[nt], 0, 0, 0);
      }
    // causal mask on diagonal tiles
    if (kt == 2 * qt2) {
#pragma unroll
      for (int nt = 0; nt < 4; nt++)
#pragma unroll
        for (int r = 0; r < 4; r++) {
          int rr = q0 + wid * 16 + quad * 4 + r, cc = kt * 64 + nt * 16 + l15;
          if (cc > rr) sv0[nt][r] = -1e30f;
        }
    }
    if (kt == jmaxall) {
#pragma unroll
      for (int nt = 0; nt < 4; nt++)
#pragma unroll
        for (int r = 0; r < 4; r++) {
          int rr = q0 + 64 + wid * 16 + quad * 4 + r, cc = kt * 64 + nt * 16 + l15;
          if (cc > rr) sv1[nt][r] = -1e30f;
        }
    }
    // per strip: exp -> sP (wave-private rows) -> PV
#pragma unroll
    for (int s = 0; s < 2; s++) {
      if (s == 0 && !do0) continue;
      const f32x4* sv = (s == 0) ? sv0 : sv1;
#pragma unroll
      for (int nt = 0; nt < 4; nt++)
#pragma unroll
        for (int r = 0; r < 4; r++) {
          float pe = __expf(sv[nt][r]);
          lsum[s][r] += pe;
          sP[(wid * 16 + quad * 4 + r) * 72 + nt * 16 + l15] = f2bf(pe);
        }
#pragma unroll
      for (int ks = 0; ks < 2; ks++) {
        bf16x8 pa = *(const bf16x8*)&sP[(wid * 16 + l15) * 72 + ks * 32 + quad * 8];
#pragma unroll
        for (int dt = 0; dt < 8; dt++) {
          bf16x8 vv = *(const bf16x8*)&sVc[(dt * 16 + l15) * 64 + (((ks * 4 + quad) ^ (l15 & 7)) & 7) * 8];
          o[s][dt] = __builtin_amdgcn_mfma_f32_16x16x32_bf16(pa, vv, o[s][dt], 0, 0, 0);
        }
      }
    }
    __syncthreads();  // drains next tile's DMA; publishes before buffer swap
  }

  // ---- epilogue: reduce row sums, repack via LDS (smem dead), coalesced uint4 stores ----
  float rs[2][4];
#pragma unroll
  for (int s = 0; s < 2; s++)
#pragma unroll
    for (int r = 0; r < 4; r++) {
      float t = lsum[s][r];
      t += __shfl_xor(t, 1); t += __shfl_xor(t, 2); t += __shfl_xor(t, 4); t += __shfl_xor(t, 8);
      rs[s][r] = t;
    }
  u16* sT = smem;  // [64][132] staging (8448 u16)
#pragma unroll
  for (int s = 0; s < 2; s++) {
    float iv[4];
#pragma unroll
    for (int r = 0; r < 4; r++) iv[r] = split ? 1.f : 1.f / rs[s][r];
#pragma unroll
    for (int dt = 0; dt < 8; dt++)
#pragma unroll
      for (int r = 0; r < 4; r++)
        sT[(wid * 16 + quad * 4 + r) * 132 + dt * 16 + l15] = f2bf(o[s][dt][r] * iv[r]);
    __syncthreads();
    if (!split) {
#pragma unroll
      for (int rep = 0; rep < 4; rep++) {
        int row = rep * 16 + (tid >> 4);
        int c8 = (tid & 15) * 8;
        uint4 v = *(const uint4*)&sT[row * 132 + c8];
        *(uint4*)(attn + ((long)(b * Sn + q0 + s * 64 + row)) * (long)Hdim + h * Dh + c8) = v;
      }
    } else {
      u16* op = (ch == 0 ? o0 : o1) + ((long)bh * Sn + q0 + s * 64) * Dh;
#pragma unroll
      for (int rep = 0; rep < 4; rep++) {
        int row = rep * 16 + (tid >> 4);
        int c8 = (tid & 15) * 8;
        uint4 v = *(const uint4*)&sT[row * 132 + c8];
        *(uint4*)(op + (long)row * Dh + c8) = v;
      }
    }
    __syncthreads();
  }
  if (split && l15 == 0) {
    float* lp = (ch == 0 ? ls0 : ls1) + (long)bh * Sn + q0;
#pragma unroll
    for (int s = 0; s < 2; s++)
#pragma unroll
      for (int r = 0; r < 4; r++) lp[s * 64 + wid * 16 + quad * 4 + r] = rs[s][r];
  }
}

// combine bf16 chunk partials for rows 1024..2047, normalize, emit attn bf16 (coalesced)
__global__ void attn_norm6_k(const u16* __restrict__ o0, const u16* __restrict__ o1,
                             const float* __restrict__ l0, const float* __restrict__ l1,
                             u16* __restrict__ attn) {
  const int gid = blockIdx.x;  // 24 bh * 64 row-groups of 16
  const int bh = gid >> 6, rb = gid & 63;
  const int row = 1024 + rb * 16 + (threadIdx.x >> 4);
  const int ch = (threadIdx.x & 15) * 8;
  const long idx = ((long)bh * Sn + row) * Dh + ch;
  union { uint4 v; u16 s[8]; } a, b2, ov;
  a.v = *(const uint4*)(o0 + idx);
  b2.v = *(const uint4*)(o1 + idx);
  const float inv = 1.f / (l0[(long)bh * Sn + row] + l1[(long)bh * Sn + row]);
#pragma unroll
  for (int k = 0; k < 8; k++) ov.s[k] = f2bf((bf2f(a.s[k]) + bf2f(b2.s[k])) * inv);
  const int b = bh / 12, h = bh % 12;
  *(uint4*)(attn + ((long)(b * Sn + row)) * (long)Hdim + h * Dh + ch) = ov.v;
}

// ---------------- host ----------------

extern "C" void kernel_launch(void* const* d_in, const int* in_sizes, int n_in,
                              void* d_out, int out_size, void* d_ws, size_t ws_size,
                              hipStream_t stream) {
  const float* hidden = (const float*)d_in[0];
  const int* pos = (const int*)d_in[1];
  const float* cosT = (const float*)d_in[2];
  const float* sinT = (const float*)d_in[3];
  const float* ln1 = (const float*)d_in[4];
  const float* ln2 = (const float*)d_in[5];
  const float* wq = (const float*)d_in[6];
  const float* wk = (const float*)d_in[7];
  const float* wv = (const float*)d_in[8];
  const float* wo = (const float*)d_in[9];
  const float* router_w = (const float*)d_in[10];
  const float* w_gate = (const float*)d_in[11];
  const float* w_up = (const float*)d_in[12];
  const float* w_down = (const float*)d_in[13];
  const float* shared_in = (const float*)d_in[14];
  const float* shared_out = (const float*)d_in[15];
  float* out = (float*)d_out;

  // ---- workspace layout with phase-based aliasing ----
  char* p = (char*)d_ws;
  auto alloc = [&](size_t bytes) -> char* {
    char* r = p; p += (bytes + 255) & ~(size_t)255; return r;
  };
  u16* wqkv_b = (u16*)alloc((size_t)2560 * Hdim * 2);
  u16* wo_b = (u16*)alloc((size_t)Hdim * Hdim * 2);
  u16* wgu_b = (u16*)alloc((size_t)NE * 1024 * Hdim * 2);
  u16* wdown_b = (u16*)alloc((size_t)NE * Hdim * IEXP * 2);
  u16* wshin_b = (u16*)alloc((size_t)2048 * Hdim * 2);
  u16* wshout_b = (u16*)alloc((size_t)Hdim * ISH * 2);
  char* regH = alloc((size_t)Tn * Hdim * 4);                // x1n | attn-partial slot0 | hidden2
  char* reg1 = alloc((size_t)Tn * 2560 * 2);                // qkvraw | attn | gu | shraw
  char* reg2 = alloc((size_t)Bn * NHq * Sn * Dh * 2);       // qbuf | x2n | shy
  char* reg3 = alloc((size_t)2 * Bn * NKVh * Sn * Dh * 2);  // kbuf+vT | act | shact
  u16* Y_b = (u16*)alloc((size_t)2 * Tn * Hdim * 2);        // also attn-partial slot1
  int* tidx = (int*)alloc(Tn * 2 * 4);
  float* tw = (float*)alloc(Tn * 2 * 4);
  int* tokslot = (int*)alloc(Tn * 2 * 4);
  int* perm = (int*)alloc(Tn * 2 * 4);
  float* slotw = (float*)alloc(Tn * 2 * 4);
  int* counts = (int*)alloc(64);
  int* seg = (int*)alloc(64);
  float* lsum0 = (float*)alloc((size_t)24 * Sn * 4);
  float* lsum1 = (float*)alloc((size_t)24 * Sn * 4);

  u16* x1n = (u16*)regH;
  float* hidden2 = (float*)regH;
  u16* opart0 = (u16*)regH;  // bf16 partials, rows>=1024 only; region free during attention
  u16* opart1 = (u16*)Y_b;   // Y written later
  u16* qkvraw = (u16*)reg1;
  u16* attn = (u16*)reg1;
  u16* gu_b = (u16*)reg1;
  u16* shraw_b = (u16*)reg1;
  u16* qbuf = (u16*)reg2;
  u16* x2n = (u16*)reg2;
  u16* shy_b = (u16*)reg2;
  u16* kbuf = (u16*)reg3;
  u16* vtbuf = kbuf + (size_t)Bn * NKVh * Sn * Dh;  // transposed V [b][hk][d][s]
  u16* act_b = (u16*)reg3;
  u16* shact_b = (u16*)reg3;

  auto cdiv = [](long a, long b) { return (int)((a + b - 1) / b); };

  // fused weight conversion
  cvt_all_k<<<(int)(B7 / 256), 256, 0, stream>>>(
      (const float4*)wq, (const float4*)wk, (const float4*)wv, (const float4*)wo,
      (const float4*)w_gate, (const float4*)w_up, (const float4*)w_down,
      (const float4*)shared_in, (const float4*)shared_out,
      (ushort4*)wqkv_b, (ushort4*)wo_b, (ushort4*)wgu_b, (ushort4*)wdown_b,
      (ushort4*)wshin_b, (ushort4*)wshout_b);

  // attention block
  rmsnorm_k<<<Tn, 256, 0, stream>>>(hidden, ln1, x1n);
  gemm_bt<0><<<dim3(2560 / 128, Tn / 128, 1), 256, 0, stream>>>(
      x1n, wqkv_b, nullptr, qkvraw, nullptr, nullptr, nullptr, nullptr, Tn, 2560, Hdim, 0);
  rope_k<<<Tn, 256, 0, stream>>>(qkvraw, pos, cosT, sinT, qbuf, kbuf);
  vt_k<<<dim3(Sn / 64, Dh / 64, Bn * NKVh), 256, 0, stream>>>(qkvraw, vtbuf);
  flash7_k<<<dim3(576, 1, 1), 256, 0, stream>>>(qbuf, kbuf, vtbuf, opart0, opart1, lsum0, lsum1, attn);
  attn_norm6_k<<<dim3(24 * 64, 1, 1), 256, 0, stream>>>(opart0, opart1, lsum0, lsum1, attn);
  gemm_bt<2><<<dim3(Hdim / 128, Tn / 128, 1), 256, 0, stream>>>(
      attn, wo_b, hidden2, nullptr, hidden, nullptr, nullptr, nullptr, Tn, Hdim, Hdim, 0);

  // MoE block
  rmsnorm_k<<<Tn, 256, 0, stream>>>(hidden2, ln2, x2n);
  router_k<<<Tn / 4, 256, 0, stream>>>(hidden2, ln2, router_w, tidx, tw);
  route_scan_k<<<1, 256, 0, stream>>>(tidx, tw, perm, slotw, tokslot, counts, seg);
  gemm_bt<0><<<dim3(1024 / 128, Tn / 128, NE), 256, 0, stream>>>(
      x2n, wgu_b, nullptr, gu_b, nullptr, perm, counts, seg, 0, 1024, Hdim, (long)1024 * Hdim);
  act_moe_k<<<cdiv((long)2 * Tn * IEXP / 8, 256), 256, 0, stream>>>(gu_b, slotw, act_b);
  gemm_bt<0><<<dim3(Hdim / 128, Tn / 128, NE), 256, 0, stream>>>(
      act_b, wdown_b, nullptr, Y_b, nullptr, nullptr, counts, seg, 0, Hdim, IEXP, (long)Hdim * IEXP);

  // shared MLP
  gemm_bt<0><<<dim3(2048 / 128, Tn / 128, 1), 256, 0, stream>>>(
      x2n, wshin_b, nullptr, shraw_b, nullptr, nullptr, nullptr, nullptr, Tn, 2048, Hdim, 0);
  act_sh_k<<<cdiv((long)Tn * ISH / 8, 256), 256, 0, stream>>>(shraw_b, shact_b);
  gemm_bt<0><<<dim3(Hdim / 128, Tn / 128, 1), 256, 0, stream>>>(
      shact_b, wshout_b, nullptr, shy_b, nullptr, nullptr, nullptr, nullptr, Tn, Hdim, ISH, 0);

  // combine
  final_k<<<cdiv((long)Tn * Hdim / 4, 256), 256, 0, stream>>>(hidden2, shy_b, Y_b, tokslot, out);
}